// Round 17
// baseline (210.252 us; speedup 1.0000x reference)
//
#include <hip/hip_runtime.h>
#include <cstdint>
#include <cstddef>

// Attention fwd (B=2,H=16,S=2048,D=64), outputs (out, p_attn) fp32.
// R17 = R16 split into TWO dispatches: attn_sums (pass 1 -> inv sums in ws)
// and attn_pv (pass 2, reads inv). Removes the correlated pass-1 window at
// kernel start where no block issues P stores (store pipe idle ~35-40us),
// letting attn_pv keep HBM writes saturated for its entire duration.
// Same math bit-for-bit; setprio, quad pass-1, pair pass-2, phase rotation
// and counted vmcnt all retained. Fallback (ws too small): R1 kernel.

typedef float f32x4 __attribute__((ext_vector_type(4)));
typedef short s16x8 __attribute__((ext_vector_type(8)));
typedef unsigned int u32;

#define S_LEN 2048
#define D_DIM 64
#define NKT   32
// 1/sqrt(64) * log2(e)
#define QSCALE 0.18033688011112042f

__device__ __forceinline__ unsigned short f2bf(float f) {
  unsigned u = __builtin_bit_cast(unsigned, f);
  u += 0x7FFFu + ((u >> 16) & 1u);   // RNE
  return (unsigned short)(u >> 16);
}

__device__ __forceinline__ f32x4 mfma16(s16x8 a, s16x8 b, f32x4 c) {
  return __builtin_amdgcn_mfma_f32_16x16x32_bf16(a, b, c, 0, 0, 0);
}

__device__ __forceinline__ void gl_lds16(const void* g, void* l) {
  __builtin_amdgcn_global_load_lds(
      (const __attribute__((address_space(1))) u32*)g,
      (__attribute__((address_space(3))) u32*)l, 16, 0, 0);
}

// ---------------- pre-pass: K and V in one dispatch ----------------
__global__ void prep_kv(const float* __restrict__ Kg, const float* __restrict__ Vg,
                        unsigned short* __restrict__ kb, unsigned short* __restrict__ vb) {
  __shared__ float tv[64 * 65];
  const int kt = blockIdx.x, bh = blockIdx.y, tid = threadIdx.x;
  const int r = tid >> 2, c0 = (tid & 3) << 4;
  if (blockIdx.z == 0) {
    const float* src = Kg + (((size_t)bh * S_LEN) + kt * 64 + r) * D_DIM + c0;
    f32x4 f0 = *(const f32x4*)(src);
    f32x4 f1 = *(const f32x4*)(src + 4);
    f32x4 f2 = *(const f32x4*)(src + 8);
    f32x4 f3 = *(const f32x4*)(src + 12);
    s16x8 h0, h1;
#pragma unroll
    for (int j = 0; j < 4; j++) {
      h0[j] = (short)f2bf(f0[j]); h0[j + 4] = (short)f2bf(f1[j]);
      h1[j] = (short)f2bf(f2[j]); h1[j + 4] = (short)f2bf(f3[j]);
    }
    char* dst = (char*)(kb + ((size_t)bh * 32 + kt) * 4096);
    const int swz = (r & 7) << 4;
    *(s16x8*)(dst + (r << 7) + (((c0 << 1) + 0)  ^ swz)) = h0;
    *(s16x8*)(dst + (r << 7) + (((c0 << 1) + 16) ^ swz)) = h1;
  } else {
    const float* src = Vg + (((size_t)bh * S_LEN) + kt * 64 + r) * D_DIM + c0;
#pragma unroll
    for (int j = 0; j < 4; j++)
      *(f32x4*)(tv + r * 65 + c0 + j * 4) = *(const f32x4*)(src + j * 4);
    __syncthreads();
    const int d = tid >> 2, k0 = (tid & 3) << 4;
    s16x8 h0, h1;
#pragma unroll
    for (int j = 0; j < 8; j++) {
      h0[j] = (short)f2bf(tv[(k0 + j) * 65 + d]);
      h1[j] = (short)f2bf(tv[(k0 + 8 + j) * 65 + d]);
    }
    char* dst = (char*)(vb + ((size_t)bh * 32 + kt) * 4096);
    const int swz = (d & 7) << 4;
    *(s16x8*)(dst + (d << 7) + (((k0 << 1) + 0)  ^ swz)) = h0;
    *(s16x8*)(dst + (d << 7) + (((k0 << 1) + 16) ^ swz)) = h1;
  }
}

// ---------------- kernel A: row sums only ----------------

__global__ __launch_bounds__(512, 4) void attn_sums(
    const float* __restrict__ Qg, const unsigned short* __restrict__ Kb,
    const int* __restrict__ Mg, float* __restrict__ invb)
{
  __shared__ __align__(16) short s_k[8][4096];     // 64 KB: 8 K tile slots
  __shared__ unsigned s_m[64];

  const int tid = threadIdx.x;
  const int w = tid >> 6, l = tid & 63, lo = l & 15, hi = l >> 4;
  const int wg = blockIdx.x;
  const int bh = (wg & 7) * 4 + ((wg >> 3) >> 4);
  const int qt = (wg >> 3) & 15;
  const int b = bh >> 4;
  const int ph = wg & 31;

  if (tid < 64) s_m[tid] = 0u;
  __syncthreads();
  {
    const int4 mv = *(const int4*)(Mg + b * S_LEN + tid * 4);
    unsigned nib = (mv.x ? 1u : 0u) | (mv.y ? 2u : 0u) |
                   (mv.z ? 4u : 0u) | (mv.w ? 8u : 0u);
    atomicOr(&s_m[tid >> 3], nib << ((tid & 7) * 4));
  }
  __syncthreads();
  const unsigned mword = s_m[l];

  const size_t bhS = (size_t)bh * S_LEN;
  const int q0w = qt * 128 + w * 16;

  const float* qsrc = Qg + (bhS + q0w + lo) * D_DIM + hi * 8;
  s16x8 bq0, bq1;
  {
    f32x4 a0 = *(const f32x4*)(qsrc);
    f32x4 a1 = *(const f32x4*)(qsrc + 4);
    f32x4 c0 = *(const f32x4*)(qsrc + 32);
    f32x4 c1 = *(const f32x4*)(qsrc + 36);
#pragma unroll
    for (int j = 0; j < 4; j++) {
      bq0[j]     = (short)f2bf(a0[j] * QSCALE);
      bq0[j + 4] = (short)f2bf(a1[j] * QSCALE);
      bq1[j]     = (short)f2bf(c0[j] * QSCALE);
      bq1[j + 4] = (short)f2bf(c1[j] * QSCALE);
    }
  }

  const char* ktile = (const char*)(Kb + bhS * D_DIM);
  char* base = (char*)s_k;
  const int swz = (lo & 7) << 4;
  const int hs  = hi << 2;

  gl_lds16(ktile + ((0 + ph) & 31) * 8192 + tid * 16, base + 0 * 8192 + tid * 16);
  gl_lds16(ktile + ((1 + ph) & 31) * 8192 + tid * 16, base + 1 * 8192 + tid * 16);
  gl_lds16(ktile + ((2 + ph) & 31) * 8192 + tid * 16, base + 2 * 8192 + tid * 16);
  gl_lds16(ktile + ((3 + ph) & 31) * 8192 + tid * 16, base + 3 * 8192 + tid * 16);

  float lacc[4] = {0.f, 0.f, 0.f, 0.f};
  for (int j = 0; j < 8; j++) {
    const int h = j & 1;
    asm volatile("s_waitcnt vmcnt(0)" ::: "memory");
    __builtin_amdgcn_s_barrier();
    __builtin_amdgcn_sched_barrier(0);
    if (j < 7) {
      const int tb = 4 * j + 4;
      char* dst = base + (h ^ 1) * 32768;
      gl_lds16(ktile + ((tb + 0 + ph) & 31) * 8192 + tid * 16, dst + 0 * 8192 + tid * 16);
      gl_lds16(ktile + ((tb + 1 + ph) & 31) * 8192 + tid * 16, dst + 1 * 8192 + tid * 16);
      gl_lds16(ktile + ((tb + 2 + ph) & 31) * 8192 + tid * 16, dst + 2 * 8192 + tid * 16);
      gl_lds16(ktile + ((tb + 3 + ph) & 31) * 8192 + tid * 16, dst + 3 * 8192 + tid * 16);
    }
#pragma unroll
    for (int t2 = 0; t2 < 4; t2++) {
      const int t = (4 * j + t2 + ph) & 31;
      const char* kc = base + h * 32768 + t2 * 8192;
      f32x4 acc[4] = {};
      __builtin_amdgcn_s_setprio(1);
#pragma unroll
      for (int nn = 0; nn < 4; nn++) {
        const int rb = (nn * 16 + lo) << 7;
        s16x8 ka0 = *(const s16x8*)(kc + rb + ((0 + hi * 16) ^ swz));
        s16x8 ka1 = *(const s16x8*)(kc + rb + ((64 + hi * 16) ^ swz));
        acc[nn] = mfma16(ka0, bq0, acc[nn]);   // A=K, B=Q -> C[key][q]
        acc[nn] = mfma16(ka1, bq1, acc[nn]);
      }
      __builtin_amdgcn_s_setprio(0);
      const unsigned w0 = (unsigned)__shfl((int)mword, 2 * t);
      const unsigned w1 = (unsigned)__shfl((int)mword, 2 * t + 1);
#pragma unroll
      for (int nn = 0; nn < 4; nn++) {
        const unsigned m4 = (((nn & 2) ? w1 : w0) >> (((nn & 1) << 4) + hs)) & 0xF;
#pragma unroll
        for (int r = 0; r < 4; r++) {
          const float e = exp2f(acc[nn][r]);
          lacc[nn] += ((m4 >> r) & 1) ? e : 0.0f;
        }
      }
    }
  }
  float lsum = (lacc[0] + lacc[1]) + (lacc[2] + lacc[3]);
  lsum += __shfl_xor(lsum, 16, 64);
  lsum += __shfl_xor(lsum, 32, 64);
  const float inv = 1.0f / lsum;
  if (l < 16) invb[bh * S_LEN + q0w + l] = inv;
}

// ---------------- kernel B: P + PV ----------------

__global__ __launch_bounds__(512, 4) void attn_pv(
    const float* __restrict__ Qg, const unsigned short* __restrict__ Kb,
    const unsigned short* __restrict__ Vb, const int* __restrict__ Mg,
    const float* __restrict__ invb, float* __restrict__ Og, float* __restrict__ Pg)
{
  __shared__ __align__(16) short s_kv[8][4096];    // K slots 0-3, V slots 4-7
  __shared__ __align__(16) short s_p[8][1024];     // P bounce (mask build aliases)

  const int tid = threadIdx.x;
  const int w = tid >> 6, l = tid & 63, lo = l & 15, hi = l >> 4;
  const int wg = blockIdx.x;
  const int bh = (wg & 7) * 4 + ((wg >> 3) >> 4);
  const int qt = (wg >> 3) & 15;
  const int b = bh >> 4;
  const int ph = wg & 31;

  unsigned* mbuild = (unsigned*)s_p;
  if (tid < 64) mbuild[tid] = 0u;
  __syncthreads();
  {
    const int4 mv = *(const int4*)(Mg + b * S_LEN + tid * 4);
    unsigned nib = (mv.x ? 1u : 0u) | (mv.y ? 2u : 0u) |
                   (mv.z ? 4u : 0u) | (mv.w ? 8u : 0u);
    atomicOr(&mbuild[tid >> 3], nib << ((tid & 7) * 4));
  }
  __syncthreads();
  const unsigned mword = mbuild[l];
  __syncthreads();   // mask reads done before s_p reused as P bounce

  const size_t bhS = (size_t)bh * S_LEN;
  const int q0w = qt * 128 + w * 16;

  const float* qsrc = Qg + (bhS + q0w + lo) * D_DIM + hi * 8;
  s16x8 bq0, bq1;
  {
    f32x4 a0 = *(const f32x4*)(qsrc);
    f32x4 a1 = *(const f32x4*)(qsrc + 4);
    f32x4 c0 = *(const f32x4*)(qsrc + 32);
    f32x4 c1 = *(const f32x4*)(qsrc + 36);
#pragma unroll
    for (int j = 0; j < 4; j++) {
      bq0[j]     = (short)f2bf(a0[j] * QSCALE);
      bq0[j + 4] = (short)f2bf(a1[j] * QSCALE);
      bq1[j]     = (short)f2bf(c0[j] * QSCALE);
      bq1[j + 4] = (short)f2bf(c1[j] * QSCALE);
    }
  }
  const float inv = invb[bh * S_LEN + q0w + lo];

  const char* ktile = (const char*)(Kb + bhS * D_DIM);
  const char* vtile = (const char*)(Vb + bhS * D_DIM);
  char* ldsk = (char*)s_kv;
  char* ldsv = (char*)s_kv + 32768;
  char* pb  = (char*)s_p[w];
  const int swz = (lo & 7) << 4;
  const int hs  = hi << 2;

  gl_lds16(ktile + ((0 + ph) & 31) * 8192 + tid * 16, ldsk + 0 * 8192 + tid * 16);
  gl_lds16(ktile + ((1 + ph) & 31) * 8192 + tid * 16, ldsk + 1 * 8192 + tid * 16);
  gl_lds16(vtile + ((0 + ph) & 31) * 8192 + tid * 16, ldsv + 0 * 8192 + tid * 16);
  gl_lds16(vtile + ((1 + ph) & 31) * 8192 + tid * 16, ldsv + 1 * 8192 + tid * 16);

  f32x4 oacc[4] = {};
  for (int j = 0; j < 16; j++) {
    const int h = j & 1;
    if (j == 0) asm volatile("s_waitcnt vmcnt(0)" ::: "memory");
    else        asm volatile("s_waitcnt vmcnt(8)" ::: "memory");
    __builtin_amdgcn_s_barrier();
    __builtin_amdgcn_sched_barrier(0);
    if (j < 15) {
      gl_lds16(ktile + ((2 * j + 2 + ph) & 31) * 8192 + tid * 16,
               ldsk + (2 * (h ^ 1)) * 8192 + tid * 16);
      gl_lds16(ktile + ((2 * j + 3 + ph) & 31) * 8192 + tid * 16,
               ldsk + (2 * (h ^ 1) + 1) * 8192 + tid * 16);
      gl_lds16(vtile + ((2 * j + 2 + ph) & 31) * 8192 + tid * 16,
               ldsv + (2 * (h ^ 1)) * 8192 + tid * 16);
      gl_lds16(vtile + ((2 * j + 3 + ph) & 31) * 8192 + tid * 16,
               ldsv + (2 * (h ^ 1) + 1) * 8192 + tid * 16);
    }
#pragma unroll
    for (int t2 = 0; t2 < 2; t2++) {
      const int t = (2 * j + t2 + ph) & 31;
      const char* kc = ldsk + (2 * h + t2) * 8192;
      const char* vc = ldsv + (2 * h + t2) * 8192;

      f32x4 acc[4] = {};
      __builtin_amdgcn_s_setprio(1);
#pragma unroll
      for (int nn = 0; nn < 4; nn++) {
        const int rb = (nn * 16 + lo) << 7;
        s16x8 ka0 = *(const s16x8*)(kc + rb + ((0 + hi * 16) ^ swz));
        s16x8 ka1 = *(const s16x8*)(kc + rb + ((64 + hi * 16) ^ swz));
        acc[nn] = mfma16(ka0, bq0, acc[nn]);
        acc[nn] = mfma16(ka1, bq1, acc[nn]);
      }
      __builtin_amdgcn_s_setprio(0);
      const unsigned w0 = (unsigned)__shfl((int)mword, 2 * t);
      const unsigned w1 = (unsigned)__shfl((int)mword, 2 * t + 1);
      const int colb = t * 64;
      float* prow = Pg + (bhS + q0w + lo) * S_LEN + colb;
#pragma unroll
      for (int nn = 0; nn < 4; nn++) {
        const unsigned m4 = (((nn & 2) ? w1 : w0) >> (((nn & 1) << 4) + hs)) & 0xF;
        f32x4 p;
#pragma unroll
        for (int r = 0; r < 4; r++) {
          const float e = exp2f(acc[nn][r]) * inv;
          p[r] = ((m4 >> r) & 1) ? e : 0.0f;
        }
        *(f32x4*)(prow + nn * 16 + hi * 4) = p;
        unsigned d0, d1;
        asm("v_cvt_pk_bf16_f32 %0, %1, %2" : "=v"(d0) : "v"(p[0]), "v"(p[1]));
        asm("v_cvt_pk_bf16_f32 %0, %1, %2" : "=v"(d1) : "v"(p[2]), "v"(p[3]));
        *(unsigned long long*)(pb + (lo << 7) + ((nn * 32 + hi * 8) ^ swz)) =
            ((unsigned long long)d1 << 32) | d0;
      }
      __builtin_amdgcn_s_setprio(1);
#pragma unroll
      for (int kk2 = 0; kk2 < 2; kk2++) {
        s16x8 bp = *(const s16x8*)(pb + (lo << 7) + ((kk2 * 64 + hi * 16) ^ swz));
#pragma unroll
        for (int dd = 0; dd < 4; dd++) {
          s16x8 va = *(const s16x8*)(vc + ((dd * 16 + lo) << 7) +
                                     ((kk2 * 64 + hi * 16) ^ swz));
          oacc[dd] = mfma16(va, bp, oacc[dd]);
        }
      }
      __builtin_amdgcn_s_setprio(0);
    }
  }
#pragma unroll
  for (int dd = 0; dd < 4; dd++)
    *(f32x4*)(Og + (bhS + q0w + lo) * D_DIM + dd * 16 + hi * 4) = oacc[dd];
}

// ---------------- fallback (R1 kernel, used if ws too small) ----------------

__device__ __forceinline__ void stage_k(const float* __restrict__ g, char* lb, int tid) {
  const int kr = tid >> 2;
  const int c0 = (tid & 3) << 4;
  const f32x4* src = (const f32x4*)(g + kr * D_DIM + c0);
  f32x4 f0 = src[0], f1 = src[1], f2 = src[2], f3 = src[3];
  s16x8 h0, h1;
#pragma unroll
  for (int j = 0; j < 4; j++) {
    h0[j] = (short)f2bf(f0[j]); h0[j + 4] = (short)f2bf(f1[j]);
    h1[j] = (short)f2bf(f2[j]); h1[j + 4] = (short)f2bf(f3[j]);
  }
  const int base = kr << 7;
  const int swz = (kr & 7) << 4;
  *(s16x8*)(lb + base + (((c0 << 1) + 0) ^ swz)) = h0;
  *(s16x8*)(lb + base + (((c0 << 1) + 16) ^ swz)) = h1;
}

__device__ __forceinline__ void stage_v(const float* __restrict__ g, char* lb, int tid) {
  const int k0 = (tid >> 3) << 1;
  const int c0 = (tid & 7) << 3;
  const f32x4* s0 = (const f32x4*)(g + k0 * D_DIM + c0);
  const f32x4* s1 = (const f32x4*)(g + (k0 + 1) * D_DIM + c0);
  f32x4 a0 = s0[0], a1 = s0[1];
  f32x4 b0 = s1[0], b1 = s1[1];
  const int kc = (k0 >> 3) & 7;
  const int kb2 = (k0 & 7) << 1;
#pragma unroll
  for (int j = 0; j < 8; j++) {
    float fa = (j < 4) ? a0[j & 3] : a1[j & 3];
    float fb = (j < 4) ? b0[j & 3] : b1[j & 3];
    unsigned u = (unsigned)f2bf(fa) | ((unsigned)f2bf(fb) << 16);
    const int d = c0 + j;
    const int off = (d << 7) + (((kc ^ j ^ (d >> 3)) & 7) << 4) + kb2;
    *(unsigned*)(lb + off) = u;
  }
}

__global__ __launch_bounds__(256, 4) void attn_fwd(
    const float* __restrict__ Qg, const float* __restrict__ Kg,
    const float* __restrict__ Vg, const int* __restrict__ Mg,
    float* __restrict__ Og, float* __restrict__ Pg)
{
  __shared__ __align__(16) float s_bias[S_LEN];
  __shared__ __align__(16) short s_k[64 * 64];
  __shared__ __align__(16) short s_v[64 * 64];
  __shared__ __align__(16) short s_p[4 * 16 * 64];

  const int tid = threadIdx.x;
  const int w = tid >> 6, l = tid & 63, lo = l & 15, hi = l >> 4;
  const int bh = blockIdx.x, qt = blockIdx.y, b = bh >> 4;

  for (int i = tid; i < S_LEN; i += 256)
    s_bias[i] = Mg[b * S_LEN + i] ? 0.0f : -INFINITY;

  const int q0 = qt * 64 + w * 16;
  const float* qptr = Qg + ((size_t)bh * S_LEN + q0 + lo) * D_DIM + hi * 8;
  s16x8 aq[2];
#pragma unroll
  for (int kk = 0; kk < 2; kk++) {
    f32x4 v0 = *(const f32x4*)(qptr + kk * 32);
    f32x4 v1 = *(const f32x4*)(qptr + kk * 32 + 4);
#pragma unroll
    for (int j = 0; j < 4; j++) {
      aq[kk][j] = (short)f2bf(v0[j] * QSCALE);
      aq[kk][j + 4] = (short)f2bf(v1[j] * QSCALE);
    }
  }
  char* kb = (char*)s_k;
  char* vb = (char*)s_v;
  char* pb = (char*)s_p + (w << 11);
  const size_t bhS = (size_t)bh * S_LEN;
  __syncthreads();

  float lsum[4] = {0.f, 0.f, 0.f, 0.f};
  for (int kt = 0; kt < NKT; kt++) {
    stage_k(Kg + (bhS + kt * 64) * D_DIM, kb, tid);
    __syncthreads();
    f32x4 acc[4] = {};
#pragma unroll
    for (int kk = 0; kk < 2; kk++)
#pragma unroll
      for (int nn = 0; nn < 4; nn++) {
        const int row = nn * 16 + lo;
        s16x8 bk = *(const s16x8*)(kb + (row << 7) +
                     ((kk * 64 + hi * 16) ^ ((row & 7) << 4)));
        acc[nn] = mfma16(aq[kk], bk, acc[nn]);
      }
    const int colb = kt * 64;
#pragma unroll
    for (int nn = 0; nn < 4; nn++) {
      const float bias = s_bias[colb + nn * 16 + lo];
#pragma unroll
      for (int r = 0; r < 4; r++)
        lsum[r] += exp2f(acc[nn][r] + bias);
    }
    __syncthreads();
  }
#pragma unroll
  for (int r = 0; r < 4; r++)
#pragma unroll
    for (int off = 1; off < 16; off <<= 1)
      lsum[r] += __shfl_xor(lsum[r], off, 64);
  float inv[4];
#pragma unroll
  for (int r = 0; r < 4; r++) inv[r] = 1.0f / lsum[r];

  f32x4 oacc[4] = {};
  const int qd0 = q0 + hi * 4;
  for (int kt = 0; kt < NKT; kt++) {
    stage_k(Kg + (bhS + kt * 64) * D_DIM, kb, tid);
    stage_v(Vg + (bhS + kt * 64) * D_DIM, vb, tid);
    __syncthreads();
    f32x4 acc[4] = {};
#pragma unroll
    for (int kk = 0; kk < 2; kk++)
#pragma unroll
      for (int nn = 0; nn < 4; nn++) {
        const int row = nn * 16 + lo;
        s16x8 bk = *(const s16x8*)(kb + (row << 7) +
                     ((kk * 64 + hi * 16) ^ ((row & 7) << 4)));
        acc[nn] = mfma16(aq[kk], bk, acc[nn]);
      }
    const int colb = kt * 64;
#pragma unroll
    for (int nn = 0; nn < 4; nn++) {
      const int col = colb + nn * 16 + lo;
      const float bias = s_bias[col];
#pragma unroll
      for (int r = 0; r < 4; r++) {
        const float p = exp2f(acc[nn][r] + bias) * inv[r];
        Pg[(bhS + (size_t)(qd0 + r)) * S_LEN + col] = p;
        const int prow = hi * 4 + r;
        *(unsigned short*)(pb + (prow << 7) +
            ((((nn * 16 + lo) << 1)) ^ ((prow & 7) << 4))) = f2bf(p);
      }
    }
#pragma unroll
    for (int kk2 = 0; kk2 < 2; kk2++) {
      s16x8 ap = *(const s16x8*)(pb + (lo << 7) +
                   ((kk2 * 64 + hi * 16) ^ ((lo & 7) << 4)));
#pragma unroll
      for (int dd = 0; dd < 4; dd++) {
        const int d = dd * 16 + lo;
        const int chunk = ((kk2 * 4 + hi) ^ (d & 7) ^ (d >> 3)) & 7;
        s16x8 bv = *(const s16x8*)(vb + (d << 7) + (chunk << 4));
        oacc[dd] = mfma16(ap, bv, oacc[dd]);
      }
    }
    __syncthreads();
  }
#pragma unroll
  for (int dd = 0; dd < 4; dd++)
#pragma unroll
    for (int r = 0; r < 4; r++)
      Og[(bhS + (size_t)(qd0 + r)) * D_DIM + dd * 16 + lo] = oacc[dd][r];
}

extern "C" void kernel_launch(void* const* d_in, const int* in_sizes, int n_in,
                              void* d_out, int out_size, void* d_ws, size_t ws_size,
                              hipStream_t stream) {
  const float* Q = (const float*)d_in[0];
  const float* K = (const float*)d_in[1];
  const float* V = (const float*)d_in[2];
  const int*   M = (const int*)d_in[3];
  float* out = (float*)d_out;
  float* P = out + (size_t)2 * 16 * 2048 * 64;

  const size_t elems = (size_t)2 * 16 * 2048 * 64;   // 4,194,304 per tensor
  const size_t need = elems * 2 * sizeof(unsigned short) + 
                      (size_t)32 * S_LEN * sizeof(float);
  if (ws_size >= need) {
    unsigned short* kb = (unsigned short*)d_ws;
    unsigned short* vb = kb + elems;
    float* invb = (float*)(vb + elems);
    prep_kv<<<dim3(32, 32, 2), 256, 0, stream>>>(K, V, kb, vb);
    attn_sums<<<dim3(512), 512, 0, stream>>>(Q, kb, M, invb);
    attn_pv<<<dim3(512), 512, 0, stream>>>(Q, kb, vb, M, invb, out, P);
  } else {
    attn_fwd<<<dim3(32, 32), dim3(256), 0, stream>>>(Q, K, V, M, out, P);
  }
}

// Round 18
// 172.169 us; speedup vs baseline: 1.2212x; 1.2212x over previous
//
#include <hip/hip_runtime.h>
#include <cstdint>
#include <cstddef>

// Attention fwd (B=2,H=16,S=2048,D=64), outputs (out, p_attn) fp32.
// R18 = exact revert to R16 (best: 170.5us). R17's two-dispatch split
// regressed -40us: stream ordering imposed a global barrier between the
// sums pass and the PV pass, destroying the inter-block phase overlap the
// monolithic kernel already had. R16 structure: bf16 pre-pass (merged K/V
// dispatch), quad-tile pass 1, pair-tile pass 2 with counted vmcnt, k-tile
// phase rotation, XCD swizzle, setprio on MFMA clusters, in-kernel Q cvt.
// Fallback (ws too small): R1 kernel.

typedef float f32x4 __attribute__((ext_vector_type(4)));
typedef short s16x8 __attribute__((ext_vector_type(8)));
typedef unsigned int u32;

#define S_LEN 2048
#define D_DIM 64
#define NKT   32
// 1/sqrt(64) * log2(e)
#define QSCALE 0.18033688011112042f

__device__ __forceinline__ unsigned short f2bf(float f) {
  unsigned u = __builtin_bit_cast(unsigned, f);
  u += 0x7FFFu + ((u >> 16) & 1u);   // RNE
  return (unsigned short)(u >> 16);
}

__device__ __forceinline__ f32x4 mfma16(s16x8 a, s16x8 b, f32x4 c) {
  return __builtin_amdgcn_mfma_f32_16x16x32_bf16(a, b, c, 0, 0, 0);
}

__device__ __forceinline__ void gl_lds16(const void* g, void* l) {
  __builtin_amdgcn_global_load_lds(
      (const __attribute__((address_space(1))) u32*)g,
      (__attribute__((address_space(3))) u32*)l, 16, 0, 0);
}

// ---------------- pre-pass: K and V in one dispatch ----------------
// z==0: K -> bf16 tile-major [bh][kt][64 x 128B], row-swizzled (r&7)<<4
// z==1: V -> bf16 TRANSPOSED tile-major [bh][kt][Vt 64 x 128B], same swizzle
__global__ void prep_kv(const float* __restrict__ Kg, const float* __restrict__ Vg,
                        unsigned short* __restrict__ kb, unsigned short* __restrict__ vb) {
  __shared__ float tv[64 * 65];
  const int kt = blockIdx.x, bh = blockIdx.y, tid = threadIdx.x;
  const int r = tid >> 2, c0 = (tid & 3) << 4;
  if (blockIdx.z == 0) {
    const float* src = Kg + (((size_t)bh * S_LEN) + kt * 64 + r) * D_DIM + c0;
    f32x4 f0 = *(const f32x4*)(src);
    f32x4 f1 = *(const f32x4*)(src + 4);
    f32x4 f2 = *(const f32x4*)(src + 8);
    f32x4 f3 = *(const f32x4*)(src + 12);
    s16x8 h0, h1;
#pragma unroll
    for (int j = 0; j < 4; j++) {
      h0[j] = (short)f2bf(f0[j]); h0[j + 4] = (short)f2bf(f1[j]);
      h1[j] = (short)f2bf(f2[j]); h1[j + 4] = (short)f2bf(f3[j]);
    }
    char* dst = (char*)(kb + ((size_t)bh * 32 + kt) * 4096);
    const int swz = (r & 7) << 4;
    *(s16x8*)(dst + (r << 7) + (((c0 << 1) + 0)  ^ swz)) = h0;
    *(s16x8*)(dst + (r << 7) + (((c0 << 1) + 16) ^ swz)) = h1;
  } else {
    const float* src = Vg + (((size_t)bh * S_LEN) + kt * 64 + r) * D_DIM + c0;
#pragma unroll
    for (int j = 0; j < 4; j++)
      *(f32x4*)(tv + r * 65 + c0 + j * 4) = *(const f32x4*)(src + j * 4);
    __syncthreads();
    const int d = tid >> 2, k0 = (tid & 3) << 4;
    s16x8 h0, h1;
#pragma unroll
    for (int j = 0; j < 8; j++) {
      h0[j] = (short)f2bf(tv[(k0 + j) * 65 + d]);
      h1[j] = (short)f2bf(tv[(k0 + 8 + j) * 65 + d]);
    }
    char* dst = (char*)(vb + ((size_t)bh * 32 + kt) * 4096);
    const int swz = (d & 7) << 4;
    *(s16x8*)(dst + (d << 7) + (((k0 << 1) + 0)  ^ swz)) = h0;
    *(s16x8*)(dst + (d << 7) + (((k0 << 1) + 16) ^ swz)) = h1;
  }
}

// ---------------- main kernel ----------------

__global__ __launch_bounds__(512, 4) void attn_main(
    const float* __restrict__ Qg, const unsigned short* __restrict__ Kb,
    const unsigned short* __restrict__ Vb, const int* __restrict__ Mg,
    float* __restrict__ Og, float* __restrict__ Pg)
{
  __shared__ __align__(16) short s_kv[8][4096];    // 64 KB: 8 tile slots
  __shared__ __align__(16) short s_p[8][1024];     // 16 KB: P bounce (mask build aliases)

  const int tid = threadIdx.x;
  const int w = tid >> 6, l = tid & 63, lo = l & 15, hi = l >> 4;
  // XCD-bijective swizzle: 512 blocks = 8 XCDs x 64; 4 bh per XCD
  const int wg = blockIdx.x;
  const int bh = (wg & 7) * 4 + ((wg >> 3) >> 4);
  const int qt = (wg >> 3) & 15;
  const int b = bh >> 4;
  const int ph = wg & 31;            // k-tile phase rotation (HBM channel spread)

  // Build 2048-bit mask in s_p's space, then move to per-lane register:
  // lane i holds mask word i (bit k of word i = mask[i*32+k]).
  unsigned* mbuild = (unsigned*)s_p;
  if (tid < 64) mbuild[tid] = 0u;
  __syncthreads();
  {
    const int4 mv = *(const int4*)(Mg + b * S_LEN + tid * 4);
    unsigned nib = (mv.x ? 1u : 0u) | (mv.y ? 2u : 0u) |
                   (mv.z ? 4u : 0u) | (mv.w ? 8u : 0u);
    atomicOr(&mbuild[tid >> 3], nib << ((tid & 7) * 4));
  }
  __syncthreads();
  const unsigned mword = mbuild[l];
  __syncthreads();   // mask reads done before s_p is reused as P bounce

  const size_t bhS = (size_t)bh * S_LEN;
  const int q0w = qt * 128 + w * 16;

  // Q (fp32) -> bf16 B-fragment in-kernel: lane holds Q[q0w+lo][kk*32+hi*8+j]
  const float* qsrc = Qg + (bhS + q0w + lo) * D_DIM + hi * 8;
  s16x8 bq0, bq1;
  {
    f32x4 a0 = *(const f32x4*)(qsrc);
    f32x4 a1 = *(const f32x4*)(qsrc + 4);
    f32x4 c0 = *(const f32x4*)(qsrc + 32);
    f32x4 c1 = *(const f32x4*)(qsrc + 36);
#pragma unroll
    for (int j = 0; j < 4; j++) {
      bq0[j]     = (short)f2bf(a0[j] * QSCALE);
      bq0[j + 4] = (short)f2bf(a1[j] * QSCALE);
      bq1[j]     = (short)f2bf(c0[j] * QSCALE);
      bq1[j + 4] = (short)f2bf(c1[j] * QSCALE);
    }
  }

  const char* ktile = (const char*)(Kb + bhS * D_DIM);
  const char* vtile = (const char*)(Vb + bhS * D_DIM);
  char* base = (char*)s_kv;          // 8 slots of 8192 B
  char* pb  = (char*)s_p[w];
  const int swz = (lo & 7) << 4;
  const int hs  = hi << 2;

  // ==== pass 1: row sums (QUAD-tile groups, double-buffered halves) ====
  gl_lds16(ktile + ((0 + ph) & 31) * 8192 + tid * 16, base + 0 * 8192 + tid * 16);
  gl_lds16(ktile + ((1 + ph) & 31) * 8192 + tid * 16, base + 1 * 8192 + tid * 16);
  gl_lds16(ktile + ((2 + ph) & 31) * 8192 + tid * 16, base + 2 * 8192 + tid * 16);
  gl_lds16(ktile + ((3 + ph) & 31) * 8192 + tid * 16, base + 3 * 8192 + tid * 16);

  float lacc[4] = {0.f, 0.f, 0.f, 0.f};
  for (int j = 0; j < 8; j++) {
    const int h = j & 1;
    asm volatile("s_waitcnt vmcnt(0)" ::: "memory");   // quad loads arrived
    __builtin_amdgcn_s_barrier();                      // all waves done with h^1
    __builtin_amdgcn_sched_barrier(0);
    if (j < 7) {                                       // prefetch next quad -> h^1
      const int tb = 4 * j + 4;
      char* dst = base + (h ^ 1) * 32768;
      gl_lds16(ktile + ((tb + 0 + ph) & 31) * 8192 + tid * 16, dst + 0 * 8192 + tid * 16);
      gl_lds16(ktile + ((tb + 1 + ph) & 31) * 8192 + tid * 16, dst + 1 * 8192 + tid * 16);
      gl_lds16(ktile + ((tb + 2 + ph) & 31) * 8192 + tid * 16, dst + 2 * 8192 + tid * 16);
      gl_lds16(ktile + ((tb + 3 + ph) & 31) * 8192 + tid * 16, dst + 3 * 8192 + tid * 16);
    }
#pragma unroll
    for (int t2 = 0; t2 < 4; t2++) {
      const int t = (4 * j + t2 + ph) & 31;
      const char* kc = base + h * 32768 + t2 * 8192;
      f32x4 acc[4] = {};
      __builtin_amdgcn_s_setprio(1);
#pragma unroll
      for (int nn = 0; nn < 4; nn++) {
        const int rb = (nn * 16 + lo) << 7;
        s16x8 ka0 = *(const s16x8*)(kc + rb + ((0 + hi * 16) ^ swz));
        s16x8 ka1 = *(const s16x8*)(kc + rb + ((64 + hi * 16) ^ swz));
        acc[nn] = mfma16(ka0, bq0, acc[nn]);   // A=K, B=Q -> C[key][q]
        acc[nn] = mfma16(ka1, bq1, acc[nn]);
      }
      __builtin_amdgcn_s_setprio(0);
      const unsigned w0 = (unsigned)__shfl((int)mword, 2 * t);
      const unsigned w1 = (unsigned)__shfl((int)mword, 2 * t + 1);
#pragma unroll
      for (int nn = 0; nn < 4; nn++) {
        const unsigned m4 = (((nn & 2) ? w1 : w0) >> (((nn & 1) << 4) + hs)) & 0xF;
#pragma unroll
        for (int r = 0; r < 4; r++) {
          const float e = exp2f(acc[nn][r]);
          lacc[nn] += ((m4 >> r) & 1) ? e : 0.0f;
        }
      }
    }
  }
  float lsum = (lacc[0] + lacc[1]) + (lacc[2] + lacc[3]);
  lsum += __shfl_xor(lsum, 16, 64);
  lsum += __shfl_xor(lsum, 32, 64);
  const float inv = 1.0f / lsum;

  __syncthreads();   // pass boundary: full drain once

  // ==== pass 2: P + PV (pair structure; K slots 0-3, V slots 4-7) ====
  char* ldsk = base;
  char* ldsv = base + 32768;
  gl_lds16(ktile + ((0 + ph) & 31) * 8192 + tid * 16, ldsk + 0 * 8192 + tid * 16);
  gl_lds16(ktile + ((1 + ph) & 31) * 8192 + tid * 16, ldsk + 1 * 8192 + tid * 16);
  gl_lds16(vtile + ((0 + ph) & 31) * 8192 + tid * 16, ldsv + 0 * 8192 + tid * 16);
  gl_lds16(vtile + ((1 + ph) & 31) * 8192 + tid * 16, ldsv + 1 * 8192 + tid * 16);

  f32x4 oacc[4] = {};
  for (int j = 0; j < 16; j++) {
    const int h = j & 1;
    // FIFO at top (j>=1): [L x4 (this pair, issued j-1), S x8 (pair j-1)]
    if (j == 0) asm volatile("s_waitcnt vmcnt(0)" ::: "memory");
    else        asm volatile("s_waitcnt vmcnt(8)" ::: "memory");
    __builtin_amdgcn_s_barrier();
    __builtin_amdgcn_sched_barrier(0);
    if (j < 15) {                                      // prefetch next pair -> h^1
      gl_lds16(ktile + ((2 * j + 2 + ph) & 31) * 8192 + tid * 16,
               ldsk + (2 * (h ^ 1)) * 8192 + tid * 16);
      gl_lds16(ktile + ((2 * j + 3 + ph) & 31) * 8192 + tid * 16,
               ldsk + (2 * (h ^ 1) + 1) * 8192 + tid * 16);
      gl_lds16(vtile + ((2 * j + 2 + ph) & 31) * 8192 + tid * 16,
               ldsv + (2 * (h ^ 1)) * 8192 + tid * 16);
      gl_lds16(vtile + ((2 * j + 3 + ph) & 31) * 8192 + tid * 16,
               ldsv + (2 * (h ^ 1) + 1) * 8192 + tid * 16);
    }
#pragma unroll
    for (int t2 = 0; t2 < 2; t2++) {
      const int t = (2 * j + t2 + ph) & 31;
      const char* kc = ldsk + (2 * h + t2) * 8192;
      const char* vc = ldsv + (2 * h + t2) * 8192;

      f32x4 acc[4] = {};
      __builtin_amdgcn_s_setprio(1);
#pragma unroll
      for (int nn = 0; nn < 4; nn++) {
        const int rb = (nn * 16 + lo) << 7;
        s16x8 ka0 = *(const s16x8*)(kc + rb + ((0 + hi * 16) ^ swz));
        s16x8 ka1 = *(const s16x8*)(kc + rb + ((64 + hi * 16) ^ swz));
        acc[nn] = mfma16(ka0, bq0, acc[nn]);
        acc[nn] = mfma16(ka1, bq1, acc[nn]);
      }
      __builtin_amdgcn_s_setprio(0);
      const unsigned w0 = (unsigned)__shfl((int)mword, 2 * t);
      const unsigned w1 = (unsigned)__shfl((int)mword, 2 * t + 1);
      const int colb = t * 64;
      float* prow = Pg + (bhS + q0w + lo) * S_LEN + colb;
#pragma unroll
      for (int nn = 0; nn < 4; nn++) {
        const unsigned m4 = (((nn & 2) ? w1 : w0) >> (((nn & 1) << 4) + hs)) & 0xF;
        f32x4 p;
#pragma unroll
        for (int r = 0; r < 4; r++) {
          const float e = exp2f(acc[nn][r]) * inv;
          p[r] = ((m4 >> r) & 1) ? e : 0.0f;
        }
        *(f32x4*)(prow + nn * 16 + hi * 4) = p;    // 4 consecutive key-cols
        unsigned d0, d1;
        asm("v_cvt_pk_bf16_f32 %0, %1, %2" : "=v"(d0) : "v"(p[0]), "v"(p[1]));
        asm("v_cvt_pk_bf16_f32 %0, %1, %2" : "=v"(d1) : "v"(p[2]), "v"(p[3]));
        *(unsigned long long*)(pb + (lo << 7) + ((nn * 32 + hi * 8) ^ swz)) =
            ((unsigned long long)d1 << 32) | d0;
      }
      // O^T = Vt * P^T : A=Vt[d][key] (LDS), B=P^T[key][q] (wave-private LDS)
      __builtin_amdgcn_s_setprio(1);
#pragma unroll
      for (int kk2 = 0; kk2 < 2; kk2++) {
        s16x8 bp = *(const s16x8*)(pb + (lo << 7) + ((kk2 * 64 + hi * 16) ^ swz));
#pragma unroll
        for (int dd = 0; dd < 4; dd++) {
          s16x8 va = *(const s16x8*)(vc + ((dd * 16 + lo) << 7) +
                                     ((kk2 * 64 + hi * 16) ^ swz));
          oacc[dd] = mfma16(va, bp, oacc[dd]);
        }
      }
      __builtin_amdgcn_s_setprio(0);
    }
  }
  // O: lane holds O[q=lo][d = dd*16 + hi*4 + r] -> f32x4 per dd
#pragma unroll
  for (int dd = 0; dd < 4; dd++)
    *(f32x4*)(Og + (bhS + q0w + lo) * D_DIM + dd * 16 + hi * 4) = oacc[dd];
}

// ---------------- fallback (R1 kernel, used if ws too small) ----------------

__device__ __forceinline__ void stage_k(const float* __restrict__ g, char* lb, int tid) {
  const int kr = tid >> 2;
  const int c0 = (tid & 3) << 4;
  const f32x4* src = (const f32x4*)(g + kr * D_DIM + c0);
  f32x4 f0 = src[0], f1 = src[1], f2 = src[2], f3 = src[3];
  s16x8 h0, h1;
#pragma unroll
  for (int j = 0; j < 4; j++) {
    h0[j] = (short)f2bf(f0[j]); h0[j + 4] = (short)f2bf(f1[j]);
    h1[j] = (short)f2bf(f2[j]); h1[j + 4] = (short)f2bf(f3[j]);
  }
  const int base = kr << 7;
  const int swz = (kr & 7) << 4;
  *(s16x8*)(lb + base + (((c0 << 1) + 0) ^ swz)) = h0;
  *(s16x8*)(lb + base + (((c0 << 1) + 16) ^ swz)) = h1;
}

__device__ __forceinline__ void stage_v(const float* __restrict__ g, char* lb, int tid) {
  const int k0 = (tid >> 3) << 1;
  const int c0 = (tid & 7) << 3;
  const f32x4* s0 = (const f32x4*)(g + k0 * D_DIM + c0);
  const f32x4* s1 = (const f32x4*)(g + (k0 + 1) * D_DIM + c0);
  f32x4 a0 = s0[0], a1 = s0[1];
  f32x4 b0 = s1[0], b1 = s1[1];
  const int kc = (k0 >> 3) & 7;
  const int kb2 = (k0 & 7) << 1;
#pragma unroll
  for (int j = 0; j < 8; j++) {
    float fa = (j < 4) ? a0[j & 3] : a1[j & 3];
    float fb = (j < 4) ? b0[j & 3] : b1[j & 3];
    unsigned u = (unsigned)f2bf(fa) | ((unsigned)f2bf(fb) << 16);
    const int d = c0 + j;
    const int off = (d << 7) + (((kc ^ j ^ (d >> 3)) & 7) << 4) + kb2;
    *(unsigned*)(lb + off) = u;
  }
}

__global__ __launch_bounds__(256, 4) void attn_fwd(
    const float* __restrict__ Qg, const float* __restrict__ Kg,
    const float* __restrict__ Vg, const int* __restrict__ Mg,
    float* __restrict__ Og, float* __restrict__ Pg)
{
  __shared__ __align__(16) float s_bias[S_LEN];
  __shared__ __align__(16) short s_k[64 * 64];
  __shared__ __align__(16) short s_v[64 * 64];
  __shared__ __align__(16) short s_p[4 * 16 * 64];

  const int tid = threadIdx.x;
  const int w = tid >> 6, l = tid & 63, lo = l & 15, hi = l >> 4;
  const int bh = blockIdx.x, qt = blockIdx.y, b = bh >> 4;

  for (int i = tid; i < S_LEN; i += 256)
    s_bias[i] = Mg[b * S_LEN + i] ? 0.0f : -INFINITY;

  const int q0 = qt * 64 + w * 16;
  const float* qptr = Qg + ((size_t)bh * S_LEN + q0 + lo) * D_DIM + hi * 8;
  s16x8 aq[2];
#pragma unroll
  for (int kk = 0; kk < 2; kk++) {
    f32x4 v0 = *(const f32x4*)(qptr + kk * 32);
    f32x4 v1 = *(const f32x4*)(qptr + kk * 32 + 4);
#pragma unroll
    for (int j = 0; j < 4; j++) {
      aq[kk][j] = (short)f2bf(v0[j] * QSCALE);
      aq[kk][j + 4] = (short)f2bf(v1[j] * QSCALE);
    }
  }
  char* kb = (char*)s_k;
  char* vb = (char*)s_v;
  char* pb = (char*)s_p + (w << 11);
  const size_t bhS = (size_t)bh * S_LEN;
  __syncthreads();

  float lsum[4] = {0.f, 0.f, 0.f, 0.f};
  for (int kt = 0; kt < NKT; kt++) {
    stage_k(Kg + (bhS + kt * 64) * D_DIM, kb, tid);
    __syncthreads();
    f32x4 acc[4] = {};
#pragma unroll
    for (int kk = 0; kk < 2; kk++)
#pragma unroll
      for (int nn = 0; nn < 4; nn++) {
        const int row = nn * 16 + lo;
        s16x8 bk = *(const s16x8*)(kb + (row << 7) +
                     ((kk * 64 + hi * 16) ^ ((row & 7) << 4)));
        acc[nn] = mfma16(aq[kk], bk, acc[nn]);
      }
    const int colb = kt * 64;
#pragma unroll
    for (int nn = 0; nn < 4; nn++) {
      const float bias = s_bias[colb + nn * 16 + lo];
#pragma unroll
      for (int r = 0; r < 4; r++)
        lsum[r] += exp2f(acc[nn][r] + bias);
    }
    __syncthreads();
  }
#pragma unroll
  for (int r = 0; r < 4; r++)
#pragma unroll
    for (int off = 1; off < 16; off <<= 1)
      lsum[r] += __shfl_xor(lsum[r], off, 64);
  float inv[4];
#pragma unroll
  for (int r = 0; r < 4; r++) inv[r] = 1.0f / lsum[r];

  f32x4 oacc[4] = {};
  const int qd0 = q0 + hi * 4;
  for (int kt = 0; kt < NKT; kt++) {
    stage_k(Kg + (bhS + kt * 64) * D_DIM, kb, tid);
    stage_v(Vg + (bhS + kt * 64) * D_DIM, vb, tid);
    __syncthreads();
    f32x4 acc[4] = {};
#pragma unroll
    for (int kk = 0; kk < 2; kk++)
#pragma unroll
      for (int nn = 0; nn < 4; nn++) {
        const int row = nn * 16 + lo;
        s16x8 bk = *(const s16x8*)(kb + (row << 7) +
                     ((kk * 64 + hi * 16) ^ ((row & 7) << 4)));
        acc[nn] = mfma16(aq[kk], bk, acc[nn]);
      }
    const int colb = kt * 64;
#pragma unroll
    for (int nn = 0; nn < 4; nn++) {
      const int col = colb + nn * 16 + lo;
      const float bias = s_bias[col];
#pragma unroll
      for (int r = 0; r < 4; r++) {
        const float p = exp2f(acc[nn][r] + bias) * inv[r];
        Pg[(bhS + (size_t)(qd0 + r)) * S_LEN + col] = p;
        const int prow = hi * 4 + r;
        *(unsigned short*)(pb + (prow << 7) +
            ((((nn * 16 + lo) << 1)) ^ ((prow & 7) << 4))) = f2bf(p);
      }
    }
#pragma unroll
    for (int kk2 = 0; kk2 < 2; kk2++) {
      s16x8 ap = *(const s16x8*)(pb + (lo << 7) +
                   ((kk2 * 64 + hi * 16) ^ ((lo & 7) << 4)));
#pragma unroll
      for (int dd = 0; dd < 4; dd++) {
        const int d = dd * 16 + lo;
        const int chunk = ((kk2 * 4 + hi) ^ (d & 7) ^ (d >> 3)) & 7;
        s16x8 bv = *(const s16x8*)(vb + (d << 7) + (chunk << 4));
        oacc[dd] = mfma16(ap, bv, oacc[dd]);
      }
    }
    __syncthreads();
  }
#pragma unroll
  for (int dd = 0; dd < 4; dd++)
#pragma unroll
    for (int r = 0; r < 4; r++)
      Og[(bhS + (size_t)(qd0 + r)) * D_DIM + dd * 16 + lo] = oacc[dd][r];
}

extern "C" void kernel_launch(void* const* d_in, const int* in_sizes, int n_in,
                              void* d_out, int out_size, void* d_ws, size_t ws_size,
                              hipStream_t stream) {
  const float* Q = (const float*)d_in[0];
  const float* K = (const float*)d_in[1];
  const float* V = (const float*)d_in[2];
  const int*   M = (const int*)d_in[3];
  float* out = (float*)d_out;
  float* P = out + (size_t)2 * 16 * 2048 * 64;

  const size_t elems = (size_t)2 * 16 * 2048 * 64;   // 4,194,304 per tensor
  if (ws_size >= elems * 2 * sizeof(unsigned short)) {
    unsigned short* kb = (unsigned short*)d_ws;
    unsigned short* vb = kb + elems;
    prep_kv<<<dim3(32, 32, 2), 256, 0, stream>>>(K, V, kb, vb);
    attn_main<<<dim3(512), 512, 0, stream>>>(Q, kb, vb, M, out, P);
  } else {
    attn_fwd<<<dim3(32, 32), dim3(256), 0, stream>>>(Q, K, V, M, out, P);
  }
}

// Round 19
// 162.714 us; speedup vs baseline: 1.2922x; 1.0581x over previous
//
#include <hip/hip_runtime.h>
#include <cstdint>
#include <cstddef>

// Attention fwd (B=2,H=16,S=2048,D=64), outputs (out, p_attn) fp32.
// R19 = R18 (=R16 best, 170-172us) + COALESCED P STORES (retest of R8's
// change, now that R10's phase rotation removed the cross-block channel
// convoy that may have masked it): P re-read from the wave-private LDS
// bounce in row-major order, expanded bf16->f32, stored as 4x256B
// contiguous segments per lane instead of 16x64B segments at 8KB stride
// (4 L2/coalescer transactions per store instr instead of 16).
// Everything else identical to R18. Fallback (ws too small): R1 kernel.

typedef float f32x4 __attribute__((ext_vector_type(4)));
typedef short s16x8 __attribute__((ext_vector_type(8)));
typedef unsigned int u32;

#define S_LEN 2048
#define D_DIM 64
#define NKT   32
// 1/sqrt(64) * log2(e)
#define QSCALE 0.18033688011112042f

__device__ __forceinline__ unsigned short f2bf(float f) {
  unsigned u = __builtin_bit_cast(unsigned, f);
  u += 0x7FFFu + ((u >> 16) & 1u);   // RNE
  return (unsigned short)(u >> 16);
}

__device__ __forceinline__ f32x4 mfma16(s16x8 a, s16x8 b, f32x4 c) {
  return __builtin_amdgcn_mfma_f32_16x16x32_bf16(a, b, c, 0, 0, 0);
}

__device__ __forceinline__ void gl_lds16(const void* g, void* l) {
  __builtin_amdgcn_global_load_lds(
      (const __attribute__((address_space(1))) u32*)g,
      (__attribute__((address_space(3))) u32*)l, 16, 0, 0);
}

// ---------------- pre-pass: K and V in one dispatch ----------------
// z==0: K -> bf16 tile-major [bh][kt][64 x 128B], row-swizzled (r&7)<<4
// z==1: V -> bf16 TRANSPOSED tile-major [bh][kt][Vt 64 x 128B], same swizzle
__global__ void prep_kv(const float* __restrict__ Kg, const float* __restrict__ Vg,
                        unsigned short* __restrict__ kb, unsigned short* __restrict__ vb) {
  __shared__ float tv[64 * 65];
  const int kt = blockIdx.x, bh = blockIdx.y, tid = threadIdx.x;
  const int r = tid >> 2, c0 = (tid & 3) << 4;
  if (blockIdx.z == 0) {
    const float* src = Kg + (((size_t)bh * S_LEN) + kt * 64 + r) * D_DIM + c0;
    f32x4 f0 = *(const f32x4*)(src);
    f32x4 f1 = *(const f32x4*)(src + 4);
    f32x4 f2 = *(const f32x4*)(src + 8);
    f32x4 f3 = *(const f32x4*)(src + 12);
    s16x8 h0, h1;
#pragma unroll
    for (int j = 0; j < 4; j++) {
      h0[j] = (short)f2bf(f0[j]); h0[j + 4] = (short)f2bf(f1[j]);
      h1[j] = (short)f2bf(f2[j]); h1[j + 4] = (short)f2bf(f3[j]);
    }
    char* dst = (char*)(kb + ((size_t)bh * 32 + kt) * 4096);
    const int swz = (r & 7) << 4;
    *(s16x8*)(dst + (r << 7) + (((c0 << 1) + 0)  ^ swz)) = h0;
    *(s16x8*)(dst + (r << 7) + (((c0 << 1) + 16) ^ swz)) = h1;
  } else {
    const float* src = Vg + (((size_t)bh * S_LEN) + kt * 64 + r) * D_DIM + c0;
#pragma unroll
    for (int j = 0; j < 4; j++)
      *(f32x4*)(tv + r * 65 + c0 + j * 4) = *(const f32x4*)(src + j * 4);
    __syncthreads();
    const int d = tid >> 2, k0 = (tid & 3) << 4;
    s16x8 h0, h1;
#pragma unroll
    for (int j = 0; j < 8; j++) {
      h0[j] = (short)f2bf(tv[(k0 + j) * 65 + d]);
      h1[j] = (short)f2bf(tv[(k0 + 8 + j) * 65 + d]);
    }
    char* dst = (char*)(vb + ((size_t)bh * 32 + kt) * 4096);
    const int swz = (d & 7) << 4;
    *(s16x8*)(dst + (d << 7) + (((k0 << 1) + 0)  ^ swz)) = h0;
    *(s16x8*)(dst + (d << 7) + (((k0 << 1) + 16) ^ swz)) = h1;
  }
}

// ---------------- main kernel ----------------

__global__ __launch_bounds__(512, 4) void attn_main(
    const float* __restrict__ Qg, const unsigned short* __restrict__ Kb,
    const unsigned short* __restrict__ Vb, const int* __restrict__ Mg,
    float* __restrict__ Og, float* __restrict__ Pg)
{
  __shared__ __align__(16) short s_kv[8][4096];    // 64 KB: 8 tile slots
  __shared__ __align__(16) short s_p[8][1024];     // 16 KB: P bounce (mask build aliases)

  const int tid = threadIdx.x;
  const int w = tid >> 6, l = tid & 63, lo = l & 15, hi = l >> 4;
  // XCD-bijective swizzle: 512 blocks = 8 XCDs x 64; 4 bh per XCD
  const int wg = blockIdx.x;
  const int bh = (wg & 7) * 4 + ((wg >> 3) >> 4);
  const int qt = (wg >> 3) & 15;
  const int b = bh >> 4;
  const int ph = wg & 31;            // k-tile phase rotation (HBM channel spread)

  // Build 2048-bit mask in s_p's space, then move to per-lane register:
  // lane i holds mask word i (bit k of word i = mask[i*32+k]).
  unsigned* mbuild = (unsigned*)s_p;
  if (tid < 64) mbuild[tid] = 0u;
  __syncthreads();
  {
    const int4 mv = *(const int4*)(Mg + b * S_LEN + tid * 4);
    unsigned nib = (mv.x ? 1u : 0u) | (mv.y ? 2u : 0u) |
                   (mv.z ? 4u : 0u) | (mv.w ? 8u : 0u);
    atomicOr(&mbuild[tid >> 3], nib << ((tid & 7) * 4));
  }
  __syncthreads();
  const unsigned mword = mbuild[l];
  __syncthreads();   // mask reads done before s_p is reused as P bounce

  const size_t bhS = (size_t)bh * S_LEN;
  const int q0w = qt * 128 + w * 16;

  // Q (fp32) -> bf16 B-fragment in-kernel: lane holds Q[q0w+lo][kk*32+hi*8+j]
  const float* qsrc = Qg + (bhS + q0w + lo) * D_DIM + hi * 8;
  s16x8 bq0, bq1;
  {
    f32x4 a0 = *(const f32x4*)(qsrc);
    f32x4 a1 = *(const f32x4*)(qsrc + 4);
    f32x4 c0 = *(const f32x4*)(qsrc + 32);
    f32x4 c1 = *(const f32x4*)(qsrc + 36);
#pragma unroll
    for (int j = 0; j < 4; j++) {
      bq0[j]     = (short)f2bf(a0[j] * QSCALE);
      bq0[j + 4] = (short)f2bf(a1[j] * QSCALE);
      bq1[j]     = (short)f2bf(c0[j] * QSCALE);
      bq1[j + 4] = (short)f2bf(c1[j] * QSCALE);
    }
  }

  const char* ktile = (const char*)(Kb + bhS * D_DIM);
  const char* vtile = (const char*)(Vb + bhS * D_DIM);
  char* base = (char*)s_kv;          // 8 slots of 8192 B
  char* pb  = (char*)s_p[w];
  const int swz = (lo & 7) << 4;
  const int hs  = hi << 2;

  // ==== pass 1: row sums (QUAD-tile groups, double-buffered halves) ====
  gl_lds16(ktile + ((0 + ph) & 31) * 8192 + tid * 16, base + 0 * 8192 + tid * 16);
  gl_lds16(ktile + ((1 + ph) & 31) * 8192 + tid * 16, base + 1 * 8192 + tid * 16);
  gl_lds16(ktile + ((2 + ph) & 31) * 8192 + tid * 16, base + 2 * 8192 + tid * 16);
  gl_lds16(ktile + ((3 + ph) & 31) * 8192 + tid * 16, base + 3 * 8192 + tid * 16);

  float lacc[4] = {0.f, 0.f, 0.f, 0.f};
  for (int j = 0; j < 8; j++) {
    const int h = j & 1;
    asm volatile("s_waitcnt vmcnt(0)" ::: "memory");   // quad loads arrived
    __builtin_amdgcn_s_barrier();                      // all waves done with h^1
    __builtin_amdgcn_sched_barrier(0);
    if (j < 7) {                                       // prefetch next quad -> h^1
      const int tb = 4 * j + 4;
      char* dst = base + (h ^ 1) * 32768;
      gl_lds16(ktile + ((tb + 0 + ph) & 31) * 8192 + tid * 16, dst + 0 * 8192 + tid * 16);
      gl_lds16(ktile + ((tb + 1 + ph) & 31) * 8192 + tid * 16, dst + 1 * 8192 + tid * 16);
      gl_lds16(ktile + ((tb + 2 + ph) & 31) * 8192 + tid * 16, dst + 2 * 8192 + tid * 16);
      gl_lds16(ktile + ((tb + 3 + ph) & 31) * 8192 + tid * 16, dst + 3 * 8192 + tid * 16);
    }
#pragma unroll
    for (int t2 = 0; t2 < 4; t2++) {
      const int t = (4 * j + t2 + ph) & 31;
      const char* kc = base + h * 32768 + t2 * 8192;
      f32x4 acc[4] = {};
      __builtin_amdgcn_s_setprio(1);
#pragma unroll
      for (int nn = 0; nn < 4; nn++) {
        const int rb = (nn * 16 + lo) << 7;
        s16x8 ka0 = *(const s16x8*)(kc + rb + ((0 + hi * 16) ^ swz));
        s16x8 ka1 = *(const s16x8*)(kc + rb + ((64 + hi * 16) ^ swz));
        acc[nn] = mfma16(ka0, bq0, acc[nn]);   // A=K, B=Q -> C[key][q]
        acc[nn] = mfma16(ka1, bq1, acc[nn]);
      }
      __builtin_amdgcn_s_setprio(0);
      const unsigned w0 = (unsigned)__shfl((int)mword, 2 * t);
      const unsigned w1 = (unsigned)__shfl((int)mword, 2 * t + 1);
#pragma unroll
      for (int nn = 0; nn < 4; nn++) {
        const unsigned m4 = (((nn & 2) ? w1 : w0) >> (((nn & 1) << 4) + hs)) & 0xF;
#pragma unroll
        for (int r = 0; r < 4; r++) {
          const float e = exp2f(acc[nn][r]);
          lacc[nn] += ((m4 >> r) & 1) ? e : 0.0f;
        }
      }
    }
  }
  float lsum = (lacc[0] + lacc[1]) + (lacc[2] + lacc[3]);
  lsum += __shfl_xor(lsum, 16, 64);
  lsum += __shfl_xor(lsum, 32, 64);
  const float inv = 1.0f / lsum;

  __syncthreads();   // pass boundary: full drain once

  // ==== pass 2: P + PV (pair structure; K slots 0-3, V slots 4-7) ====
  char* ldsk = base;
  char* ldsv = base + 32768;
  gl_lds16(ktile + ((0 + ph) & 31) * 8192 + tid * 16, ldsk + 0 * 8192 + tid * 16);
  gl_lds16(ktile + ((1 + ph) & 31) * 8192 + tid * 16, ldsk + 1 * 8192 + tid * 16);
  gl_lds16(vtile + ((0 + ph) & 31) * 8192 + tid * 16, ldsv + 0 * 8192 + tid * 16);
  gl_lds16(vtile + ((1 + ph) & 31) * 8192 + tid * 16, ldsv + 1 * 8192 + tid * 16);

  f32x4 oacc[4] = {};
  for (int j = 0; j < 16; j++) {
    const int h = j & 1;
    // FIFO at top (j>=1): [L x4 (this pair, issued j-1), S x8 (pair j-1)]
    if (j == 0) asm volatile("s_waitcnt vmcnt(0)" ::: "memory");
    else        asm volatile("s_waitcnt vmcnt(8)" ::: "memory");
    __builtin_amdgcn_s_barrier();
    __builtin_amdgcn_sched_barrier(0);
    if (j < 15) {                                      // prefetch next pair -> h^1
      gl_lds16(ktile + ((2 * j + 2 + ph) & 31) * 8192 + tid * 16,
               ldsk + (2 * (h ^ 1)) * 8192 + tid * 16);
      gl_lds16(ktile + ((2 * j + 3 + ph) & 31) * 8192 + tid * 16,
               ldsk + (2 * (h ^ 1) + 1) * 8192 + tid * 16);
      gl_lds16(vtile + ((2 * j + 2 + ph) & 31) * 8192 + tid * 16,
               ldsv + (2 * (h ^ 1)) * 8192 + tid * 16);
      gl_lds16(vtile + ((2 * j + 3 + ph) & 31) * 8192 + tid * 16,
               ldsv + (2 * (h ^ 1) + 1) * 8192 + tid * 16);
    }
#pragma unroll
    for (int t2 = 0; t2 < 2; t2++) {
      const int t = (2 * j + t2 + ph) & 31;
      const char* kc = ldsk + (2 * h + t2) * 8192;
      const char* vc = ldsv + (2 * h + t2) * 8192;

      f32x4 acc[4] = {};
      __builtin_amdgcn_s_setprio(1);
#pragma unroll
      for (int nn = 0; nn < 4; nn++) {
        const int rb = (nn * 16 + lo) << 7;
        s16x8 ka0 = *(const s16x8*)(kc + rb + ((0 + hi * 16) ^ swz));
        s16x8 ka1 = *(const s16x8*)(kc + rb + ((64 + hi * 16) ^ swz));
        acc[nn] = mfma16(ka0, bq0, acc[nn]);
        acc[nn] = mfma16(ka1, bq1, acc[nn]);
      }
      __builtin_amdgcn_s_setprio(0);
      const unsigned w0 = (unsigned)__shfl((int)mword, 2 * t);
      const unsigned w1 = (unsigned)__shfl((int)mword, 2 * t + 1);
      const int colb = t * 64;
      // normalized P -> bf16 -> wave-private LDS (PV A-source AND store source)
#pragma unroll
      for (int nn = 0; nn < 4; nn++) {
        const unsigned m4 = (((nn & 2) ? w1 : w0) >> (((nn & 1) << 4) + hs)) & 0xF;
        f32x4 p;
#pragma unroll
        for (int r = 0; r < 4; r++) {
          const float e = exp2f(acc[nn][r]) * inv;
          p[r] = ((m4 >> r) & 1) ? e : 0.0f;
        }
        unsigned d0, d1;
        asm("v_cvt_pk_bf16_f32 %0, %1, %2" : "=v"(d0) : "v"(p[0]), "v"(p[1]));
        asm("v_cvt_pk_bf16_f32 %0, %1, %2" : "=v"(d1) : "v"(p[2]), "v"(p[3]));
        *(unsigned long long*)(pb + (lo << 7) + ((nn * 32 + hi * 8) ^ swz)) =
            ((unsigned long long)d1 << 32) | d0;
      }
      // O^T = Vt * P^T : A=Vt[d][key] (LDS), B=P^T[key][q] (wave-private LDS)
      __builtin_amdgcn_s_setprio(1);
#pragma unroll
      for (int kk2 = 0; kk2 < 2; kk2++) {
        s16x8 bp = *(const s16x8*)(pb + (lo << 7) + ((kk2 * 64 + hi * 16) ^ swz));
#pragma unroll
        for (int dd = 0; dd < 4; dd++) {
          s16x8 va = *(const s16x8*)(vc + ((dd * 16 + lo) << 7) +
                                     ((kk2 * 64 + hi * 16) ^ swz));
          oacc[dd] = mfma16(va, bp, oacc[dd]);
        }
      }
      __builtin_amdgcn_s_setprio(0);
      // Coalesced P store: lane l -> rows {i*4 + (l>>4)}, cols (l&15)*4..+3.
      // 16 consecutive lanes cover 256B contiguous of one row (4 transactions
      // per instr instead of 16).
      {
        const int qrr = l >> 4;            // 0..3
        const int c0s = (l & 15) << 2;     // 0,4,..,60
        float* pout = Pg + (bhS + q0w) * S_LEN + colb + c0s;
#pragma unroll
        for (int i = 0; i < 4; i++) {
          const int q2 = i * 4 + qrr;
          unsigned long long pk = *(const unsigned long long*)(
              pb + (q2 << 7) + ((c0s << 1) ^ ((q2 & 7) << 4)));
          unsigned u0 = (unsigned)pk, u1 = (unsigned)(pk >> 32);
          f32x4 pf;
          pf[0] = __builtin_bit_cast(float, u0 << 16);
          pf[1] = __builtin_bit_cast(float, u0 & 0xFFFF0000u);
          pf[2] = __builtin_bit_cast(float, u1 << 16);
          pf[3] = __builtin_bit_cast(float, u1 & 0xFFFF0000u);
          *(f32x4*)(pout + (size_t)q2 * S_LEN) = pf;
        }
      }
    }
  }
  // O: lane holds O[q=lo][d = dd*16 + hi*4 + r] -> f32x4 per dd
#pragma unroll
  for (int dd = 0; dd < 4; dd++)
    *(f32x4*)(Og + (bhS + q0w + lo) * D_DIM + dd * 16 + hi * 4) = oacc[dd];
}

// ---------------- fallback (R1 kernel, used if ws too small) ----------------

__device__ __forceinline__ void stage_k(const float* __restrict__ g, char* lb, int tid) {
  const int kr = tid >> 2;
  const int c0 = (tid & 3) << 4;
  const f32x4* src = (const f32x4*)(g + kr * D_DIM + c0);
  f32x4 f0 = src[0], f1 = src[1], f2 = src[2], f3 = src[3];
  s16x8 h0, h1;
#pragma unroll
  for (int j = 0; j < 4; j++) {
    h0[j] = (short)f2bf(f0[j]); h0[j + 4] = (short)f2bf(f1[j]);
    h1[j] = (short)f2bf(f2[j]); h1[j + 4] = (short)f2bf(f3[j]);
  }
  const int base = kr << 7;
  const int swz = (kr & 7) << 4;
  *(s16x8*)(lb + base + (((c0 << 1) + 0) ^ swz)) = h0;
  *(s16x8*)(lb + base + (((c0 << 1) + 16) ^ swz)) = h1;
}

__device__ __forceinline__ void stage_v(const float* __restrict__ g, char* lb, int tid) {
  const int k0 = (tid >> 3) << 1;
  const int c0 = (tid & 7) << 3;
  const f32x4* s0 = (const f32x4*)(g + k0 * D_DIM + c0);
  const f32x4* s1 = (const f32x4*)(g + (k0 + 1) * D_DIM + c0);
  f32x4 a0 = s0[0], a1 = s0[1];
  f32x4 b0 = s1[0], b1 = s1[1];
  const int kc = (k0 >> 3) & 7;
  const int kb2 = (k0 & 7) << 1;
#pragma unroll
  for (int j = 0; j < 8; j++) {
    float fa = (j < 4) ? a0[j & 3] : a1[j & 3];
    float fb = (j < 4) ? b0[j & 3] : b1[j & 3];
    unsigned u = (unsigned)f2bf(fa) | ((unsigned)f2bf(fb) << 16);
    const int d = c0 + j;
    const int off = (d << 7) + (((kc ^ j ^ (d >> 3)) & 7) << 4) + kb2;
    *(unsigned*)(lb + off) = u;
  }
}

__global__ __launch_bounds__(256, 4) void attn_fwd(
    const float* __restrict__ Qg, const float* __restrict__ Kg,
    const float* __restrict__ Vg, const int* __restrict__ Mg,
    float* __restrict__ Og, float* __restrict__ Pg)
{
  __shared__ __align__(16) float s_bias[S_LEN];
  __shared__ __align__(16) short s_k[64 * 64];
  __shared__ __align__(16) short s_v[64 * 64];
  __shared__ __align__(16) short s_p[4 * 16 * 64];

  const int tid = threadIdx.x;
  const int w = tid >> 6, l = tid & 63, lo = l & 15, hi = l >> 4;
  const int bh = blockIdx.x, qt = blockIdx.y, b = bh >> 4;

  for (int i = tid; i < S_LEN; i += 256)
    s_bias[i] = Mg[b * S_LEN + i] ? 0.0f : -INFINITY;

  const int q0 = qt * 64 + w * 16;
  const float* qptr = Qg + ((size_t)bh * S_LEN + q0 + lo) * D_DIM + hi * 8;
  s16x8 aq[2];
#pragma unroll
  for (int kk = 0; kk < 2; kk++) {
    f32x4 v0 = *(const f32x4*)(qptr + kk * 32);
    f32x4 v1 = *(const f32x4*)(qptr + kk * 32 + 4);
#pragma unroll
    for (int j = 0; j < 4; j++) {
      aq[kk][j] = (short)f2bf(v0[j] * QSCALE);
      aq[kk][j + 4] = (short)f2bf(v1[j] * QSCALE);
    }
  }
  char* kb = (char*)s_k;
  char* vb = (char*)s_v;
  char* pb = (char*)s_p + (w << 11);
  const size_t bhS = (size_t)bh * S_LEN;
  __syncthreads();

  float lsum[4] = {0.f, 0.f, 0.f, 0.f};
  for (int kt = 0; kt < NKT; kt++) {
    stage_k(Kg + (bhS + kt * 64) * D_DIM, kb, tid);
    __syncthreads();
    f32x4 acc[4] = {};
#pragma unroll
    for (int kk = 0; kk < 2; kk++)
#pragma unroll
      for (int nn = 0; nn < 4; nn++) {
        const int row = nn * 16 + lo;
        s16x8 bk = *(const s16x8*)(kb + (row << 7) +
                     ((kk * 64 + hi * 16) ^ ((row & 7) << 4)));
        acc[nn] = mfma16(aq[kk], bk, acc[nn]);
      }
    const int colb = kt * 64;
#pragma unroll
    for (int nn = 0; nn < 4; nn++) {
      const float bias = s_bias[colb + nn * 16 + lo];
#pragma unroll
      for (int r = 0; r < 4; r++)
        lsum[r] += exp2f(acc[nn][r] + bias);
    }
    __syncthreads();
  }
#pragma unroll
  for (int r = 0; r < 4; r++)
#pragma unroll
    for (int off = 1; off < 16; off <<= 1)
      lsum[r] += __shfl_xor(lsum[r], off, 64);
  float inv[4];
#pragma unroll
  for (int r = 0; r < 4; r++) inv[r] = 1.0f / lsum[r];

  f32x4 oacc[4] = {};
  const int qd0 = q0 + hi * 4;
  for (int kt = 0; kt < NKT; kt++) {
    stage_k(Kg + (bhS + kt * 64) * D_DIM, kb, tid);
    stage_v(Vg + (bhS + kt * 64) * D_DIM, vb, tid);
    __syncthreads();
    f32x4 acc[4] = {};
#pragma unroll
    for (int kk = 0; kk < 2; kk++)
#pragma unroll
      for (int nn = 0; nn < 4; nn++) {
        const int row = nn * 16 + lo;
        s16x8 bk = *(const s16x8*)(kb + (row << 7) +
                     ((kk * 64 + hi * 16) ^ ((row & 7) << 4)));
        acc[nn] = mfma16(aq[kk], bk, acc[nn]);
      }
    const int colb = kt * 64;
#pragma unroll
    for (int nn = 0; nn < 4; nn++) {
      const int col = colb + nn * 16 + lo;
      const float bias = s_bias[col];
#pragma unroll
      for (int r = 0; r < 4; r++) {
        const float p = exp2f(acc[nn][r] + bias) * inv[r];
        Pg[(bhS + (size_t)(qd0 + r)) * S_LEN + col] = p;
        const int prow = hi * 4 + r;
        *(unsigned short*)(pb + (prow << 7) +
            ((((nn * 16 + lo) << 1)) ^ ((prow & 7) << 4))) = f2bf(p);
      }
    }
#pragma unroll
    for (int kk2 = 0; kk2 < 2; kk2++) {
      s16x8 ap = *(const s16x8*)(pb + (lo << 7) +
                   ((kk2 * 64 + hi * 16) ^ ((lo & 7) << 4)));
#pragma unroll
      for (int dd = 0; dd < 4; dd++) {
        const int d = dd * 16 + lo;
        const int chunk = ((kk2 * 4 + hi) ^ (d & 7) ^ (d >> 3)) & 7;
        s16x8 bv = *(const s16x8*)(vb + (d << 7) + (chunk << 4));
        oacc[dd] = mfma16(ap, bv, oacc[dd]);
      }
    }
    __syncthreads();
  }
#pragma unroll
  for (int dd = 0; dd < 4; dd++)
#pragma unroll
    for (int r = 0; r < 4; r++)
      Og[(bhS + (size_t)(qd0 + r)) * D_DIM + dd * 16 + lo] = oacc[dd][r];
}

extern "C" void kernel_launch(void* const* d_in, const int* in_sizes, int n_in,
                              void* d_out, int out_size, void* d_ws, size_t ws_size,
                              hipStream_t stream) {
  const float* Q = (const float*)d_in[0];
  const float* K = (const float*)d_in[1];
  const float* V = (const float*)d_in[2];
  const int*   M = (const int*)d_in[3];
  float* out = (float*)d_out;
  float* P = out + (size_t)2 * 16 * 2048 * 64;

  const size_t elems = (size_t)2 * 16 * 2048 * 64;   // 4,194,304 per tensor
  if (ws_size >= elems * 2 * sizeof(unsigned short)) {
    unsigned short* kb = (unsigned short*)d_ws;
    unsigned short* vb = kb + elems;
    prep_kv<<<dim3(32, 32, 2), 256, 0, stream>>>(K, V, kb, vb);
    attn_main<<<dim3(512), 512, 0, stream>>>(Q, kb, vb, M, out, P);
  } else {
    attn_fwd<<<dim3(32, 32), dim3(256), 0, stream>>>(Q, K, V, M, out, P);
  }
}

// Round 20
// 147.731 us; speedup vs baseline: 1.4232x; 1.1014x over previous
//
#include <hip/hip_runtime.h>
#include <cstdint>
#include <cstddef>

// Attention fwd (B=2,H=16,S=2048,D=64), outputs (out, p_attn) fp32.
// R20 = R19 (best: 162.7us) + NON-TEMPORAL flag on the COALESCED P store.
// R12's nt regression was with 64B (partial-L2-line) segments - nt forced
// partial-line writes to memory (RMW). R19's 256B contiguous segments are
// full lines, so nt now only removes L2 allocate/evict for 537MB of
// write-once data, keeping L2 for K/V. O stores stay normal (still 16B
// scattered - the pattern nt hurt). Single variable vs R19.
// Fallback (ws too small): R1 kernel.

typedef float f32x4 __attribute__((ext_vector_type(4)));
typedef short s16x8 __attribute__((ext_vector_type(8)));
typedef unsigned int u32;

#define S_LEN 2048
#define D_DIM 64
#define NKT   32
// 1/sqrt(64) * log2(e)
#define QSCALE 0.18033688011112042f

__device__ __forceinline__ unsigned short f2bf(float f) {
  unsigned u = __builtin_bit_cast(unsigned, f);
  u += 0x7FFFu + ((u >> 16) & 1u);   // RNE
  return (unsigned short)(u >> 16);
}

__device__ __forceinline__ f32x4 mfma16(s16x8 a, s16x8 b, f32x4 c) {
  return __builtin_amdgcn_mfma_f32_16x16x32_bf16(a, b, c, 0, 0, 0);
}

__device__ __forceinline__ void gl_lds16(const void* g, void* l) {
  __builtin_amdgcn_global_load_lds(
      (const __attribute__((address_space(1))) u32*)g,
      (__attribute__((address_space(3))) u32*)l, 16, 0, 0);
}

// ---------------- pre-pass: K and V in one dispatch ----------------
// z==0: K -> bf16 tile-major [bh][kt][64 x 128B], row-swizzled (r&7)<<4
// z==1: V -> bf16 TRANSPOSED tile-major [bh][kt][Vt 64 x 128B], same swizzle
__global__ void prep_kv(const float* __restrict__ Kg, const float* __restrict__ Vg,
                        unsigned short* __restrict__ kb, unsigned short* __restrict__ vb) {
  __shared__ float tv[64 * 65];
  const int kt = blockIdx.x, bh = blockIdx.y, tid = threadIdx.x;
  const int r = tid >> 2, c0 = (tid & 3) << 4;
  if (blockIdx.z == 0) {
    const float* src = Kg + (((size_t)bh * S_LEN) + kt * 64 + r) * D_DIM + c0;
    f32x4 f0 = *(const f32x4*)(src);
    f32x4 f1 = *(const f32x4*)(src + 4);
    f32x4 f2 = *(const f32x4*)(src + 8);
    f32x4 f3 = *(const f32x4*)(src + 12);
    s16x8 h0, h1;
#pragma unroll
    for (int j = 0; j < 4; j++) {
      h0[j] = (short)f2bf(f0[j]); h0[j + 4] = (short)f2bf(f1[j]);
      h1[j] = (short)f2bf(f2[j]); h1[j + 4] = (short)f2bf(f3[j]);
    }
    char* dst = (char*)(kb + ((size_t)bh * 32 + kt) * 4096);
    const int swz = (r & 7) << 4;
    *(s16x8*)(dst + (r << 7) + (((c0 << 1) + 0)  ^ swz)) = h0;
    *(s16x8*)(dst + (r << 7) + (((c0 << 1) + 16) ^ swz)) = h1;
  } else {
    const float* src = Vg + (((size_t)bh * S_LEN) + kt * 64 + r) * D_DIM + c0;
#pragma unroll
    for (int j = 0; j < 4; j++)
      *(f32x4*)(tv + r * 65 + c0 + j * 4) = *(const f32x4*)(src + j * 4);
    __syncthreads();
    const int d = tid >> 2, k0 = (tid & 3) << 4;
    s16x8 h0, h1;
#pragma unroll
    for (int j = 0; j < 8; j++) {
      h0[j] = (short)f2bf(tv[(k0 + j) * 65 + d]);
      h1[j] = (short)f2bf(tv[(k0 + 8 + j) * 65 + d]);
    }
    char* dst = (char*)(vb + ((size_t)bh * 32 + kt) * 4096);
    const int swz = (d & 7) << 4;
    *(s16x8*)(dst + (d << 7) + (((k0 << 1) + 0)  ^ swz)) = h0;
    *(s16x8*)(dst + (d << 7) + (((k0 << 1) + 16) ^ swz)) = h1;
  }
}

// ---------------- main kernel ----------------

__global__ __launch_bounds__(512, 4) void attn_main(
    const float* __restrict__ Qg, const unsigned short* __restrict__ Kb,
    const unsigned short* __restrict__ Vb, const int* __restrict__ Mg,
    float* __restrict__ Og, float* __restrict__ Pg)
{
  __shared__ __align__(16) short s_kv[8][4096];    // 64 KB: 8 tile slots
  __shared__ __align__(16) short s_p[8][1024];     // 16 KB: P bounce (mask build aliases)

  const int tid = threadIdx.x;
  const int w = tid >> 6, l = tid & 63, lo = l & 15, hi = l >> 4;
  // XCD-bijective swizzle: 512 blocks = 8 XCDs x 64; 4 bh per XCD
  const int wg = blockIdx.x;
  const int bh = (wg & 7) * 4 + ((wg >> 3) >> 4);
  const int qt = (wg >> 3) & 15;
  const int b = bh >> 4;
  const int ph = wg & 31;            // k-tile phase rotation (HBM channel spread)

  // Build 2048-bit mask in s_p's space, then move to per-lane register:
  // lane i holds mask word i (bit k of word i = mask[i*32+k]).
  unsigned* mbuild = (unsigned*)s_p;
  if (tid < 64) mbuild[tid] = 0u;
  __syncthreads();
  {
    const int4 mv = *(const int4*)(Mg + b * S_LEN + tid * 4);
    unsigned nib = (mv.x ? 1u : 0u) | (mv.y ? 2u : 0u) |
                   (mv.z ? 4u : 0u) | (mv.w ? 8u : 0u);
    atomicOr(&mbuild[tid >> 3], nib << ((tid & 7) * 4));
  }
  __syncthreads();
  const unsigned mword = mbuild[l];
  __syncthreads();   // mask reads done before s_p is reused as P bounce

  const size_t bhS = (size_t)bh * S_LEN;
  const int q0w = qt * 128 + w * 16;

  // Q (fp32) -> bf16 B-fragment in-kernel: lane holds Q[q0w+lo][kk*32+hi*8+j]
  const float* qsrc = Qg + (bhS + q0w + lo) * D_DIM + hi * 8;
  s16x8 bq0, bq1;
  {
    f32x4 a0 = *(const f32x4*)(qsrc);
    f32x4 a1 = *(const f32x4*)(qsrc + 4);
    f32x4 c0 = *(const f32x4*)(qsrc + 32);
    f32x4 c1 = *(const f32x4*)(qsrc + 36);
#pragma unroll
    for (int j = 0; j < 4; j++) {
      bq0[j]     = (short)f2bf(a0[j] * QSCALE);
      bq0[j + 4] = (short)f2bf(a1[j] * QSCALE);
      bq1[j]     = (short)f2bf(c0[j] * QSCALE);
      bq1[j + 4] = (short)f2bf(c1[j] * QSCALE);
    }
  }

  const char* ktile = (const char*)(Kb + bhS * D_DIM);
  const char* vtile = (const char*)(Vb + bhS * D_DIM);
  char* base = (char*)s_kv;          // 8 slots of 8192 B
  char* pb  = (char*)s_p[w];
  const int swz = (lo & 7) << 4;
  const int hs  = hi << 2;

  // ==== pass 1: row sums (QUAD-tile groups, double-buffered halves) ====
  gl_lds16(ktile + ((0 + ph) & 31) * 8192 + tid * 16, base + 0 * 8192 + tid * 16);
  gl_lds16(ktile + ((1 + ph) & 31) * 8192 + tid * 16, base + 1 * 8192 + tid * 16);
  gl_lds16(ktile + ((2 + ph) & 31) * 8192 + tid * 16, base + 2 * 8192 + tid * 16);
  gl_lds16(ktile + ((3 + ph) & 31) * 8192 + tid * 16, base + 3 * 8192 + tid * 16);

  float lacc[4] = {0.f, 0.f, 0.f, 0.f};
  for (int j = 0; j < 8; j++) {
    const int h = j & 1;
    asm volatile("s_waitcnt vmcnt(0)" ::: "memory");   // quad loads arrived
    __builtin_amdgcn_s_barrier();                      // all waves done with h^1
    __builtin_amdgcn_sched_barrier(0);
    if (j < 7) {                                       // prefetch next quad -> h^1
      const int tb = 4 * j + 4;
      char* dst = base + (h ^ 1) * 32768;
      gl_lds16(ktile + ((tb + 0 + ph) & 31) * 8192 + tid * 16, dst + 0 * 8192 + tid * 16);
      gl_lds16(ktile + ((tb + 1 + ph) & 31) * 8192 + tid * 16, dst + 1 * 8192 + tid * 16);
      gl_lds16(ktile + ((tb + 2 + ph) & 31) * 8192 + tid * 16, dst + 2 * 8192 + tid * 16);
      gl_lds16(ktile + ((tb + 3 + ph) & 31) * 8192 + tid * 16, dst + 3 * 8192 + tid * 16);
    }
#pragma unroll
    for (int t2 = 0; t2 < 4; t2++) {
      const int t = (4 * j + t2 + ph) & 31;
      const char* kc = base + h * 32768 + t2 * 8192;
      f32x4 acc[4] = {};
      __builtin_amdgcn_s_setprio(1);
#pragma unroll
      for (int nn = 0; nn < 4; nn++) {
        const int rb = (nn * 16 + lo) << 7;
        s16x8 ka0 = *(const s16x8*)(kc + rb + ((0 + hi * 16) ^ swz));
        s16x8 ka1 = *(const s16x8*)(kc + rb + ((64 + hi * 16) ^ swz));
        acc[nn] = mfma16(ka0, bq0, acc[nn]);   // A=K, B=Q -> C[key][q]
        acc[nn] = mfma16(ka1, bq1, acc[nn]);
      }
      __builtin_amdgcn_s_setprio(0);
      const unsigned w0 = (unsigned)__shfl((int)mword, 2 * t);
      const unsigned w1 = (unsigned)__shfl((int)mword, 2 * t + 1);
#pragma unroll
      for (int nn = 0; nn < 4; nn++) {
        const unsigned m4 = (((nn & 2) ? w1 : w0) >> (((nn & 1) << 4) + hs)) & 0xF;
#pragma unroll
        for (int r = 0; r < 4; r++) {
          const float e = exp2f(acc[nn][r]);
          lacc[nn] += ((m4 >> r) & 1) ? e : 0.0f;
        }
      }
    }
  }
  float lsum = (lacc[0] + lacc[1]) + (lacc[2] + lacc[3]);
  lsum += __shfl_xor(lsum, 16, 64);
  lsum += __shfl_xor(lsum, 32, 64);
  const float inv = 1.0f / lsum;

  __syncthreads();   // pass boundary: full drain once

  // ==== pass 2: P + PV (pair structure; K slots 0-3, V slots 4-7) ====
  char* ldsk = base;
  char* ldsv = base + 32768;
  gl_lds16(ktile + ((0 + ph) & 31) * 8192 + tid * 16, ldsk + 0 * 8192 + tid * 16);
  gl_lds16(ktile + ((1 + ph) & 31) * 8192 + tid * 16, ldsk + 1 * 8192 + tid * 16);
  gl_lds16(vtile + ((0 + ph) & 31) * 8192 + tid * 16, ldsv + 0 * 8192 + tid * 16);
  gl_lds16(vtile + ((1 + ph) & 31) * 8192 + tid * 16, ldsv + 1 * 8192 + tid * 16);

  f32x4 oacc[4] = {};
  for (int j = 0; j < 16; j++) {
    const int h = j & 1;
    // FIFO at top (j>=1): [L x4 (this pair, issued j-1), S x8 (pair j-1)]
    if (j == 0) asm volatile("s_waitcnt vmcnt(0)" ::: "memory");
    else        asm volatile("s_waitcnt vmcnt(8)" ::: "memory");
    __builtin_amdgcn_s_barrier();
    __builtin_amdgcn_sched_barrier(0);
    if (j < 15) {                                      // prefetch next pair -> h^1
      gl_lds16(ktile + ((2 * j + 2 + ph) & 31) * 8192 + tid * 16,
               ldsk + (2 * (h ^ 1)) * 8192 + tid * 16);
      gl_lds16(ktile + ((2 * j + 3 + ph) & 31) * 8192 + tid * 16,
               ldsk + (2 * (h ^ 1) + 1) * 8192 + tid * 16);
      gl_lds16(vtile + ((2 * j + 2 + ph) & 31) * 8192 + tid * 16,
               ldsv + (2 * (h ^ 1)) * 8192 + tid * 16);
      gl_lds16(vtile + ((2 * j + 3 + ph) & 31) * 8192 + tid * 16,
               ldsv + (2 * (h ^ 1) + 1) * 8192 + tid * 16);
    }
#pragma unroll
    for (int t2 = 0; t2 < 2; t2++) {
      const int t = (2 * j + t2 + ph) & 31;
      const char* kc = ldsk + (2 * h + t2) * 8192;
      const char* vc = ldsv + (2 * h + t2) * 8192;

      f32x4 acc[4] = {};
      __builtin_amdgcn_s_setprio(1);
#pragma unroll
      for (int nn = 0; nn < 4; nn++) {
        const int rb = (nn * 16 + lo) << 7;
        s16x8 ka0 = *(const s16x8*)(kc + rb + ((0 + hi * 16) ^ swz));
        s16x8 ka1 = *(const s16x8*)(kc + rb + ((64 + hi * 16) ^ swz));
        acc[nn] = mfma16(ka0, bq0, acc[nn]);
        acc[nn] = mfma16(ka1, bq1, acc[nn]);
      }
      __builtin_amdgcn_s_setprio(0);
      const unsigned w0 = (unsigned)__shfl((int)mword, 2 * t);
      const unsigned w1 = (unsigned)__shfl((int)mword, 2 * t + 1);
      const int colb = t * 64;
      // normalized P -> bf16 -> wave-private LDS (PV A-source AND store source)
#pragma unroll
      for (int nn = 0; nn < 4; nn++) {
        const unsigned m4 = (((nn & 2) ? w1 : w0) >> (((nn & 1) << 4) + hs)) & 0xF;
        f32x4 p;
#pragma unroll
        for (int r = 0; r < 4; r++) {
          const float e = exp2f(acc[nn][r]) * inv;
          p[r] = ((m4 >> r) & 1) ? e : 0.0f;
        }
        unsigned d0, d1;
        asm("v_cvt_pk_bf16_f32 %0, %1, %2" : "=v"(d0) : "v"(p[0]), "v"(p[1]));
        asm("v_cvt_pk_bf16_f32 %0, %1, %2" : "=v"(d1) : "v"(p[2]), "v"(p[3]));
        *(unsigned long long*)(pb + (lo << 7) + ((nn * 32 + hi * 8) ^ swz)) =
            ((unsigned long long)d1 << 32) | d0;
      }
      // O^T = Vt * P^T : A=Vt[d][key] (LDS), B=P^T[key][q] (wave-private LDS)
      __builtin_amdgcn_s_setprio(1);
#pragma unroll
      for (int kk2 = 0; kk2 < 2; kk2++) {
        s16x8 bp = *(const s16x8*)(pb + (lo << 7) + ((kk2 * 64 + hi * 16) ^ swz));
#pragma unroll
        for (int dd = 0; dd < 4; dd++) {
          s16x8 va = *(const s16x8*)(vc + ((dd * 16 + lo) << 7) +
                                     ((kk2 * 64 + hi * 16) ^ swz));
          oacc[dd] = mfma16(va, bp, oacc[dd]);
        }
      }
      __builtin_amdgcn_s_setprio(0);
      // Coalesced P store (non-temporal): lane l -> rows {i*4+(l>>4)},
      // cols (l&15)*4..+3. 16 lanes cover 256B contiguous (full L2 lines).
      {
        const int qrr = l >> 4;            // 0..3
        const int c0s = (l & 15) << 2;     // 0,4,..,60
        float* pout = Pg + (bhS + q0w) * S_LEN + colb + c0s;
#pragma unroll
        for (int i = 0; i < 4; i++) {
          const int q2 = i * 4 + qrr;
          unsigned long long pk = *(const unsigned long long*)(
              pb + (q2 << 7) + ((c0s << 1) ^ ((q2 & 7) << 4)));
          unsigned u0 = (unsigned)pk, u1 = (unsigned)(pk >> 32);
          f32x4 pf;
          pf[0] = __builtin_bit_cast(float, u0 << 16);
          pf[1] = __builtin_bit_cast(float, u0 & 0xFFFF0000u);
          pf[2] = __builtin_bit_cast(float, u1 << 16);
          pf[3] = __builtin_bit_cast(float, u1 & 0xFFFF0000u);
          __builtin_nontemporal_store(pf, (f32x4*)(pout + (size_t)q2 * S_LEN));
        }
      }
    }
  }
  // O: lane holds O[q=lo][d = dd*16 + hi*4 + r] -> f32x4 per dd
#pragma unroll
  for (int dd = 0; dd < 4; dd++)
    *(f32x4*)(Og + (bhS + q0w + lo) * D_DIM + dd * 16 + hi * 4) = oacc[dd];
}

// ---------------- fallback (R1 kernel, used if ws too small) ----------------

__device__ __forceinline__ void stage_k(const float* __restrict__ g, char* lb, int tid) {
  const int kr = tid >> 2;
  const int c0 = (tid & 3) << 4;
  const f32x4* src = (const f32x4*)(g + kr * D_DIM + c0);
  f32x4 f0 = src[0], f1 = src[1], f2 = src[2], f3 = src[3];
  s16x8 h0, h1;
#pragma unroll
  for (int j = 0; j < 4; j++) {
    h0[j] = (short)f2bf(f0[j]); h0[j + 4] = (short)f2bf(f1[j]);
    h1[j] = (short)f2bf(f2[j]); h1[j + 4] = (short)f2bf(f3[j]);
  }
  const int base = kr << 7;
  const int swz = (kr & 7) << 4;
  *(s16x8*)(lb + base + (((c0 << 1) + 0) ^ swz)) = h0;
  *(s16x8*)(lb + base + (((c0 << 1) + 16) ^ swz)) = h1;
}

__device__ __forceinline__ void stage_v(const float* __restrict__ g, char* lb, int tid) {
  const int k0 = (tid >> 3) << 1;
  const int c0 = (tid & 7) << 3;
  const f32x4* s0 = (const f32x4*)(g + k0 * D_DIM + c0);
  const f32x4* s1 = (const f32x4*)(g + (k0 + 1) * D_DIM + c0);
  f32x4 a0 = s0[0], a1 = s0[1];
  f32x4 b0 = s1[0], b1 = s1[1];
  const int kc = (k0 >> 3) & 7;
  const int kb2 = (k0 & 7) << 1;
#pragma unroll
  for (int j = 0; j < 8; j++) {
    float fa = (j < 4) ? a0[j & 3] : a1[j & 3];
    float fb = (j < 4) ? b0[j & 3] : b1[j & 3];
    unsigned u = (unsigned)f2bf(fa) | ((unsigned)f2bf(fb) << 16);
    const int d = c0 + j;
    const int off = (d << 7) + (((kc ^ j ^ (d >> 3)) & 7) << 4) + kb2;
    *(unsigned*)(lb + off) = u;
  }
}

__global__ __launch_bounds__(256, 4) void attn_fwd(
    const float* __restrict__ Qg, const float* __restrict__ Kg,
    const float* __restrict__ Vg, const int* __restrict__ Mg,
    float* __restrict__ Og, float* __restrict__ Pg)
{
  __shared__ __align__(16) float s_bias[S_LEN];
  __shared__ __align__(16) short s_k[64 * 64];
  __shared__ __align__(16) short s_v[64 * 64];
  __shared__ __align__(16) short s_p[4 * 16 * 64];

  const int tid = threadIdx.x;
  const int w = tid >> 6, l = tid & 63, lo = l & 15, hi = l >> 4;
  const int bh = blockIdx.x, qt = blockIdx.y, b = bh >> 4;

  for (int i = tid; i < S_LEN; i += 256)
    s_bias[i] = Mg[b * S_LEN + i] ? 0.0f : -INFINITY;

  const int q0 = qt * 64 + w * 16;
  const float* qptr = Qg + ((size_t)bh * S_LEN + q0 + lo) * D_DIM + hi * 8;
  s16x8 aq[2];
#pragma unroll
  for (int kk = 0; kk < 2; kk++) {
    f32x4 v0 = *(const f32x4*)(qptr + kk * 32);
    f32x4 v1 = *(const f32x4*)(qptr + kk * 32 + 4);
#pragma unroll
    for (int j = 0; j < 4; j++) {
      aq[kk][j] = (short)f2bf(v0[j] * QSCALE);
      aq[kk][j + 4] = (short)f2bf(v1[j] * QSCALE);
    }
  }
  char* kb = (char*)s_k;
  char* vb = (char*)s_v;
  char* pb = (char*)s_p + (w << 11);
  const size_t bhS = (size_t)bh * S_LEN;
  __syncthreads();

  float lsum[4] = {0.f, 0.f, 0.f, 0.f};
  for (int kt = 0; kt < NKT; kt++) {
    stage_k(Kg + (bhS + kt * 64) * D_DIM, kb, tid);
    __syncthreads();
    f32x4 acc[4] = {};
#pragma unroll
    for (int kk = 0; kk < 2; kk++)
#pragma unroll
      for (int nn = 0; nn < 4; nn++) {
        const int row = nn * 16 + lo;
        s16x8 bk = *(const s16x8*)(kb + (row << 7) +
                     ((kk * 64 + hi * 16) ^ ((row & 7) << 4)));
        acc[nn] = mfma16(aq[kk], bk, acc[nn]);
      }
    const int colb = kt * 64;
#pragma unroll
    for (int nn = 0; nn < 4; nn++) {
      const float bias = s_bias[colb + nn * 16 + lo];
#pragma unroll
      for (int r = 0; r < 4; r++)
        lsum[r] += exp2f(acc[nn][r] + bias);
    }
    __syncthreads();
  }
#pragma unroll
  for (int r = 0; r < 4; r++)
#pragma unroll
    for (int off = 1; off < 16; off <<= 1)
      lsum[r] += __shfl_xor(lsum[r], off, 64);
  float inv[4];
#pragma unroll
  for (int r = 0; r < 4; r++) inv[r] = 1.0f / lsum[r];

  f32x4 oacc[4] = {};
  const int qd0 = q0 + hi * 4;
  for (int kt = 0; kt < NKT; kt++) {
    stage_k(Kg + (bhS + kt * 64) * D_DIM, kb, tid);
    stage_v(Vg + (bhS + kt * 64) * D_DIM, vb, tid);
    __syncthreads();
    f32x4 acc[4] = {};
#pragma unroll
    for (int kk = 0; kk < 2; kk++)
#pragma unroll
      for (int nn = 0; nn < 4; nn++) {
        const int row = nn * 16 + lo;
        s16x8 bk = *(const s16x8*)(kb + (row << 7) +
                     ((kk * 64 + hi * 16) ^ ((row & 7) << 4)));
        acc[nn] = mfma16(aq[kk], bk, acc[nn]);
      }
    const int colb = kt * 64;
#pragma unroll
    for (int nn = 0; nn < 4; nn++) {
      const int col = colb + nn * 16 + lo;
      const float bias = s_bias[col];
#pragma unroll
      for (int r = 0; r < 4; r++) {
        const float p = exp2f(acc[nn][r] + bias) * inv[r];
        Pg[(bhS + (size_t)(qd0 + r)) * S_LEN + col] = p;
        const int prow = hi * 4 + r;
        *(unsigned short*)(pb + (prow << 7) +
            ((((nn * 16 + lo) << 1)) ^ ((prow & 7) << 4))) = f2bf(p);
      }
    }
#pragma unroll
    for (int kk2 = 0; kk2 < 2; kk2++) {
      s16x8 ap = *(const s16x8*)(pb + (lo << 7) +
                   ((kk2 * 64 + hi * 16) ^ ((lo & 7) << 4)));
#pragma unroll
      for (int dd = 0; dd < 4; dd++) {
        const int d = dd * 16 + lo;
        const int chunk = ((kk2 * 4 + hi) ^ (d & 7) ^ (d >> 3)) & 7;
        s16x8 bv = *(const s16x8*)(vb + (d << 7) + (chunk << 4));
        oacc[dd] = mfma16(ap, bv, oacc[dd]);
      }
    }
    __syncthreads();
  }
#pragma unroll
  for (int dd = 0; dd < 4; dd++)
#pragma unroll
    for (int r = 0; r < 4; r++)
      Og[(bhS + (size_t)(qd0 + r)) * D_DIM + dd * 16 + lo] = oacc[dd][r];
}

extern "C" void kernel_launch(void* const* d_in, const int* in_sizes, int n_in,
                              void* d_out, int out_size, void* d_ws, size_t ws_size,
                              hipStream_t stream) {
  const float* Q = (const float*)d_in[0];
  const float* K = (const float*)d_in[1];
  const float* V = (const float*)d_in[2];
  const int*   M = (const int*)d_in[3];
  float* out = (float*)d_out;
  float* P = out + (size_t)2 * 16 * 2048 * 64;

  const size_t elems = (size_t)2 * 16 * 2048 * 64;   // 4,194,304 per tensor
  if (ws_size >= elems * 2 * sizeof(unsigned short)) {
    unsigned short* kb = (unsigned short*)d_ws;
    unsigned short* vb = kb + elems;
    prep_kv<<<dim3(32, 32, 2), 256, 0, stream>>>(K, V, kb, vb);
    attn_main<<<dim3(512), 512, 0, stream>>>(Q, kb, vb, M, out, P);
  } else {
    attn_fwd<<<dim3(32, 32), dim3(256), 0, stream>>>(Q, K, V, M, out, P);
  }
}